// Round 16
// baseline (175.416 us; speedup 1.0000x reference)
//
#include <hip/hip_runtime.h>
#include <hip/hip_bf16.h>
#include <math.h>

#define DIM   768
#define HID   128
#define H2    256
#define NENT  128
#define SPAN  16
#define NCLS  5

// ---- ws layout (bytes) ----
// poolB  bf16 [3][128][256]             @ 0          (196,608)
// hepN   bf16 [b][k][i]                 @ 196608     (8,388,608)
// tepN   bf16 [b][k][j]                 @ 8585216    (8,388,608)
// TclsB  bf16 [m][c][b]                 @ 16973824   (655,360)
// WB     bf16 [3][768][768]             @ 17629184   (3,538,944)  dead after gates
// tokB   bf16 [3][2048][768]            @ 21168128   (9,437,184)  dead after gates
// tmp30  bf16 [b][a][k]                 @ 21168128   (16,777,216) p1->gemm2
// tmp31  bf16 [b][a][k]                 @ 37945344   (16,777,216) p1->gemm2
// gatesB bf16 [3][2048][768]            @ 58060800   (9,437,184)  gates->poolep
// predT  fp32 [k*5+m][i][j]             @ 21168128   (41,943,040) step3->transpose
// peak <= 67,497,984 B (proven budget)
#define POOLB_OFF  0
#define HEPB_OFF   196608
#define TEPB_OFF   (HEPB_OFF + 8388608)
#define TCLSB_OFF  (TEPB_OFF + 8388608)
#define WB_OFF     (TCLSB_OFF + 655360)
#define TOKB_OFF   21168128
#define TMP30_OFF  21168128
#define TMP31_OFF  (TMP30_OFF + 16777216)
#define GATESB_OFF 58060800
#define PREDT_OFF  21168128

typedef __attribute__((ext_vector_type(8))) short bf16x8;
typedef __attribute__((ext_vector_type(4))) float f32x4;

__device__ __forceinline__ float sigmoidf_(float x) { return 1.0f / (1.0f + __expf(-x)); }

__device__ __forceinline__ unsigned short f2bf(float x) {
    __hip_bfloat16 h = __float2bfloat16(x);
    return *reinterpret_cast<unsigned short*>(&h);
}
__device__ __forceinline__ float bf2f(unsigned short u) {
    unsigned int v = ((unsigned int)u) << 16;
    float f; __builtin_memcpy(&f, &v, 4); return f;
}

// ---------------- prep: wconv + conv_tcls + gather_toks fused ----------------
__global__ __launch_bounds__(256)
void prep_kernel(const float* __restrict__ Whf, const float* __restrict__ Whb,
                 const float* __restrict__ Wtf, const float* __restrict__ Wtb,
                 const float* __restrict__ Wef, const float* __restrict__ Web,
                 const float* __restrict__ Tcls, const float* __restrict__ enc,
                 const int* __restrict__ idx_h, const int* __restrict__ idx_t,
                 const int* __restrict__ idx_e,
                 unsigned short* __restrict__ WB, unsigned short* __restrict__ TB,
                 unsigned short* __restrict__ tokB)
{
    const int bb = blockIdx.x;
    const int tid = threadIdx.x;
    if (bb < 1728) {
        int gid = bb * 256 + tid;                        // < 442368
        int t2  = gid / 73728;
        int rem = gid % 73728;
        int n   = rem / 192;
        int c4  = rem % 192;
        int gate = n >> 7, j = n & 127;
        int srow = (gate == 0) ? j : (gate == 1) ? 256 + j : 384 + j;
        const float* W = (t2 == 0) ? Whf : (t2 == 1) ? Whb : (t2 == 2) ? Wtf :
                         (t2 == 3) ? Wtb : (t2 == 4) ? Wef : Web;
        float4 v = ((const float4*)(W + srow * DIM))[c4];
        unsigned short* d = WB + ((size_t)(t2 * 384 + n)) * DIM + c4 * 4;
        d[0] = f2bf(v.x); d[1] = f2bf(v.y); d[2] = f2bf(v.z); d[3] = f2bf(v.w);
    } else if (bb < 3008) {
        int idx = (bb - 1728) * 256 + tid;               // < 327680
        int b = idx / (NCLS * H2);
        int r = idx % (NCLS * H2);
        int m = r >> 8, c = r & 255;
        TB[((m << 8) + c) * H2 + b] = f2bf(Tcls[idx]);
    } else {
        int gid = (bb - 3008) * 256 + tid;               // < 6144*192
        int r  = gid / 192, c4 = gid % 192;
        int type = r >> 11;
        int rem  = r & 2047;
        const int* idx = (type == 0) ? idx_h : (type == 1) ? idx_t : idx_e;
        int row = idx[rem];
        float4 v = ((const float4*)(enc + (size_t)row * DIM))[c4];
        unsigned short h4[4] = { f2bf(v.x), f2bf(v.y), f2bf(v.z), f2bf(v.w) };
        *(uint2*)(tokB + (size_t)r * DIM + c4 * 4) = *(uint2*)h4;
    }
}

// ---------------- gates GEMM (NT), LDS-staged 2-phase double-buffer; bf16 out ----------------
__global__ __launch_bounds__(256)
void gates_mfma(const unsigned short* __restrict__ tokB,
                const unsigned short* __restrict__ WB,
                unsigned short* __restrict__ gatesB)
{
    __shared__ unsigned short As[2][128 * 64];
    __shared__ unsigned short Bs[2][128 * 64];
    const int lbid = ((int)blockIdx.x & 7) * 36 + ((int)blockIdx.x >> 3);  // bijective
    const int type = lbid / 96;
    const int rem  = lbid % 96;
    const int mb0  = (rem / 6) * 128;
    const int nb0  = (rem % 6) * 128;
    const int tid = threadIdx.x;
    const int w = tid >> 6, l = tid & 63;
    const int lr = l & 15, lg = l >> 4;
    const unsigned short* A = tokB + (size_t)type * 2048 * DIM + (size_t)mb0 * DIM;
    const unsigned short* B = WB   + (size_t)type * 768  * DIM + (size_t)nb0 * DIM;

    const int sr0 = tid >> 3;
    const int sc  = tid & 7;

    bf16x8 ra[4], rb[4];
    #define LOADT(kt)                                                        \
        {                                                                    \
            const int koff = (kt) * 64 + sc * 8;                             \
            _Pragma("unroll")                                                \
            for (int p = 0; p < 4; ++p) {                                    \
                int rr = sr0 + p * 32;                                       \
                ra[p] = *(const bf16x8*)(A + (size_t)rr * DIM + koff);       \
                rb[p] = *(const bf16x8*)(B + (size_t)rr * DIM + koff);       \
            }                                                                \
        }
    #define WRITET(buf)                                                      \
        {                                                                    \
            _Pragma("unroll")                                                \
            for (int p = 0; p < 4; ++p) {                                    \
                int rr = sr0 + p * 32;                                       \
                int bo = (rr * 128 + sc * 16) ^ ((rr & 7) << 4);             \
                *(bf16x8*)((char*)As[buf] + bo) = ra[p];                     \
                *(bf16x8*)((char*)Bs[buf] + bo) = rb[p];                     \
            }                                                                \
        }

    f32x4 acc[4][4];
    #pragma unroll
    for (int mt = 0; mt < 4; ++mt)
        #pragma unroll
        for (int nt = 0; nt < 4; ++nt) acc[mt][nt] = (f32x4){0.f, 0.f, 0.f, 0.f};

    const int am0 = (w & 1) * 64;
    const int bn0 = (w >> 1) * 64;

    LOADT(0);
    WRITET(0);
    __syncthreads();

    int cur = 0;
    #pragma unroll 1
    for (int kt = 0; kt < 12; ++kt) {
        if (kt + 1 < 12) LOADT(kt + 1);

        #pragma unroll
        for (int ks = 0; ks < 2; ++ks) {
            bf16x8 af[4], bf[4];
            #pragma unroll
            for (int mt = 0; mt < 4; ++mt) {
                int rr = am0 + mt * 16 + lr;
                int bo = (rr * 128 + ks * 64 + lg * 16) ^ ((rr & 7) << 4);
                af[mt] = *(const bf16x8*)((const char*)As[cur] + bo);
            }
            #pragma unroll
            for (int nt = 0; nt < 4; ++nt) {
                int rr = bn0 + nt * 16 + lr;
                int bo = (rr * 128 + ks * 64 + lg * 16) ^ ((rr & 7) << 4);
                bf[nt] = *(const bf16x8*)((const char*)Bs[cur] + bo);
            }
            #pragma unroll
            for (int mt = 0; mt < 4; ++mt)
                #pragma unroll
                for (int nt = 0; nt < 4; ++nt)
                    acc[mt][nt] = __builtin_amdgcn_mfma_f32_16x16x32_bf16(af[mt], bf[nt], acc[mt][nt], 0, 0, 0);
        }

        if (kt + 1 < 12) {
            WRITET(cur ^ 1);
        }
        __syncthreads();
        cur ^= 1;
    }
    #undef LOADT
    #undef WRITET

    unsigned short* C = gatesB + (size_t)type * 2048 * 768 + (size_t)mb0 * 768 + nb0;
    #pragma unroll
    for (int mt = 0; mt < 4; ++mt)
        #pragma unroll
        for (int nt = 0; nt < 4; ++nt)
            #pragma unroll
            for (int r = 0; r < 4; ++r)
                C[(size_t)(am0 + mt * 16 + lg * 4 + r) * 768 + bn0 + nt * 16 + lr] = f2bf(acc[mt][nt][r]);
}

// ---------------- pool epilogue (bf16 gates) ----------------
__global__ __launch_bounds__(256)
void pool_epilogue(const unsigned short* __restrict__ gatesB,
                   const float* __restrict__ bhf, const float* __restrict__ bhb,
                   const float* __restrict__ btf, const float* __restrict__ btb,
                   const float* __restrict__ bef, const float* __restrict__ beb,
                   unsigned short* __restrict__ poolB)
{
    const int type = blockIdx.x >> 7;
    const int ent  = blockIdx.x & 127;
    const int tid  = threadIdx.x;
    const int dir  = tid >> 7;
    const int j    = tid & 127;
    const float* Bv = (type == 0) ? (dir ? bhb : bhf)
                    : (type == 1) ? (dir ? btb : btf)
                                  : (dir ? beb : bef);
    const float bi = Bv[j], bg = Bv[2 * HID + j], bo = Bv[3 * HID + j];
    const unsigned short* g0 = gatesB + ((size_t)type * 2048 + ent * 16) * 768 + dir * 384 + j;
    float hmax = -1e30f;
    #pragma unroll
    for (int ll = 0; ll < SPAN; ++ll) {
        const unsigned short* gr = g0 + ll * 768;
        float iv = sigmoidf_(bf2f(gr[0])   + bi);
        float gv = tanhf(   bf2f(gr[128]) + bg);
        float ov = sigmoidf_(bf2f(gr[256]) + bo);
        hmax = fmaxf(hmax, ov * tanhf(iv * gv));
    }
    poolB[(size_t)(type * NENT + ent) * H2 + dir * HID + j] = f2bf(hmax);
}

// ---------------- p1_direct: NO LDS, NO BARRIER -- direct per-wave T loads -> MFMA ------
// W[a][k] = sum_c T[a][b][c]*Ee[k][c] -> tmp3[b][a][k]
// grid 2048 = t(2) x b(256) x aq(4); 256 thr = 4 waves (aw 2 x kw 2); wave = 32a x 64k.
// Lane loads its 32B fp32 A-fragment directly (16 rows x 128B segments), converts in-reg.
// Loads stay continuously in flight (no phase structure); ~64 VGPR, 0 LDS -> high occupancy.
__global__ __launch_bounds__(256)
void p1_direct(const unsigned short* __restrict__ EeB,
               const float* __restrict__ T0, const float* __restrict__ T1,
               unsigned short* __restrict__ tmp30, unsigned short* __restrict__ tmp31)
{
    const int bid = blockIdx.x;
    const int t  = bid >> 10;
    const int b  = (bid >> 2) & 255;
    const int aq = bid & 3;
    const float* T = t ? T1 : T0;
    unsigned short* outp = t ? tmp31 : tmp30;
    const int tid = threadIdx.x;
    const int w = tid >> 6, l = tid & 63;
    const int lr = l & 15, lg = l >> 4;
    const int aw = (w & 1) * 32;           // wave a-base within 64
    const int kw = (w >> 1) * 64;          // wave k-base
    const int a0 = aq * 64 + aw;

    f32x4 acc[2][4];
    #pragma unroll
    for (int mt = 0; mt < 2; ++mt)
        #pragma unroll
        for (int nt = 0; nt < 4; ++nt) acc[mt][nt] = (f32x4){0.f, 0.f, 0.f, 0.f};

    const float* row0 = T + ((size_t)(a0 +      lr) * 256 + b) * 256;
    const float* row1 = T + ((size_t)(a0 + 16 + lr) * 256 + b) * 256;

    #pragma unroll
    for (int ks = 0; ks < 8; ++ks) {
        const int co = ks * 32 + lg * 8;
        float4 u0 = ((const float4*)(row0 + co))[0];
        float4 u1 = ((const float4*)(row0 + co))[1];
        float4 v0 = ((const float4*)(row1 + co))[0];
        float4 v1 = ((const float4*)(row1 + co))[1];
        bf16x8 af0, af1;
        {
            unsigned short* p0 = (unsigned short*)&af0;
            p0[0]=f2bf(u0.x); p0[1]=f2bf(u0.y); p0[2]=f2bf(u0.z); p0[3]=f2bf(u0.w);
            p0[4]=f2bf(u1.x); p0[5]=f2bf(u1.y); p0[6]=f2bf(u1.z); p0[7]=f2bf(u1.w);
            unsigned short* p1 = (unsigned short*)&af1;
            p1[0]=f2bf(v0.x); p1[1]=f2bf(v0.y); p1[2]=f2bf(v0.z); p1[3]=f2bf(v0.w);
            p1[4]=f2bf(v1.x); p1[5]=f2bf(v1.y); p1[6]=f2bf(v1.z); p1[7]=f2bf(v1.w);
        }
        #pragma unroll
        for (int nt = 0; nt < 4; ++nt) {
            bf16x8 bf = *(const bf16x8*)(EeB + (kw + nt * 16 + lr) * H2 + co);
            acc[0][nt] = __builtin_amdgcn_mfma_f32_16x16x32_bf16(af0, bf, acc[0][nt], 0, 0, 0);
            acc[1][nt] = __builtin_amdgcn_mfma_f32_16x16x32_bf16(af1, bf, acc[1][nt], 0, 0, 0);
        }
    }

    // ---- write tmp3[b][a][k]
    #pragma unroll
    for (int mt = 0; mt < 2; ++mt)
        #pragma unroll
        for (int nt = 0; nt < 4; ++nt)
            #pragma unroll
            for (int r = 0; r < 4; ++r) {
                int a_ = a0 + mt * 16 + lg * 4 + r;
                int k_ = kw + nt * 16 + lr;
                outp[((size_t)b * 256 + a_) * 128 + k_] = f2bf(acc[mt][nt][r]);
            }
}

// ---------------- gemm2: block (t, b) -- contiguous 64KB tmp3 read, transpose-stage ----
// out[b][k][i] = sum_a tmp3[b][a][k] * Hx[i][a]
__global__ __launch_bounds__(512)
void gemm2_mfma(const unsigned short* __restrict__ HeB, const unsigned short* __restrict__ TeB,
                const unsigned short* __restrict__ tmp30, const unsigned short* __restrict__ tmp31,
                unsigned short* __restrict__ hepN, unsigned short* __restrict__ tepN)
{
    __shared__ unsigned short WT[128 * 256];
    const int bid = blockIdx.x;
    const int t = bid >> 8;
    const int b = bid & 255;
    const unsigned short* src = (t ? tmp31 : tmp30) + (size_t)b * 32768;
    const unsigned short* Hx = t ? TeB : HeB;
    unsigned short* outp = (t ? tepN : hepN) + (size_t)b * 16384;
    const int tid = threadIdx.x;
    const int w = tid >> 6, l = tid & 63;
    const int lr = l & 15, lg = l >> 4;

    // ---- transpose-stage [256a][128k] -> WT[k][a] swz
    {
        const int a0 = tid >> 4;
        const int k8 = (tid & 15) * 8;
        #pragma unroll
        for (int it = 0; it < 8; ++it) {
            int aa = it * 32 + a0;
            bf16x8 v = *(const bf16x8*)(src + aa * 128 + k8);
            #pragma unroll
            for (int j = 0; j < 8; ++j) {
                int kk = k8 + j;                       // kk&7 == j
                int bo = (kk * 512 + aa * 2) ^ (j << 4);
                *(unsigned short*)((char*)WT + bo) = ((unsigned short*)&v)[j];
            }
        }
    }
    __syncthreads();

    // ---- GEMM: M=128 k, N=128 i, K=256 a
    const int kw = (w & 1) * 64;
    const int iw = (w >> 1) * 32;
    f32x4 acc[4][2];
    #pragma unroll
    for (int mt = 0; mt < 4; ++mt)
        #pragma unroll
        for (int nt = 0; nt < 2; ++nt) acc[mt][nt] = (f32x4){0.f, 0.f, 0.f, 0.f};

    #pragma unroll
    for (int ks = 0; ks < 8; ++ks) {
        bf16x8 af[4], bf[2];
        #pragma unroll
        for (int mt = 0; mt < 4; ++mt) {
            int kr = kw + mt * 16 + lr;
            int bo = (kr * 512 + (ks * 32 + lg * 8) * 2) ^ ((kr & 7) << 4);
            af[mt] = *(const bf16x8*)((const char*)WT + bo);
        }
        #pragma unroll
        for (int nt = 0; nt < 2; ++nt)
            bf[nt] = *(const bf16x8*)(Hx + (iw + nt * 16 + lr) * H2 + ks * 32 + lg * 8);
        #pragma unroll
        for (int mt = 0; mt < 4; ++mt)
            #pragma unroll
            for (int nt = 0; nt < 2; ++nt)
                acc[mt][nt] = __builtin_amdgcn_mfma_f32_16x16x32_bf16(af[mt], bf[nt], acc[mt][nt], 0, 0, 0);
    }
    #pragma unroll
    for (int mt = 0; mt < 4; ++mt)
        #pragma unroll
        for (int nt = 0; nt < 2; ++nt)
            #pragma unroll
            for (int r = 0; r < 4; ++r) {
                int k_ = kw + mt * 16 + lg * 4 + r;
                int i_ = iw + nt * 16 + lr;
                outp[k_ * 128 + i_] = f2bf(acc[mt][nt][r]);
            }
}

// ---------------- step3: block per (k, j-half); m-loop inside ----------------
__global__ __launch_bounds__(512)
void step3_mfma(const unsigned short* __restrict__ hepN,  // [256 beta][128 k][128 i]
                const unsigned short* __restrict__ tepN,  // [256 b][128 k][128 j]
                const unsigned short* __restrict__ TclsB, // [m][c][b]
                float* __restrict__ predT)
{
    __shared__ unsigned short hepS[128 * 256];
    __shared__ unsigned short tepS[64 * 256];
    __shared__ unsigned short WS[64 * 256];
    const int lbid = (blockIdx.x & 7) * 32 + (blockIdx.x >> 3);
    const int k  = lbid >> 1;
    const int jh = lbid & 1;
    const int tid = threadIdx.x;
    const int w  = tid >> 6;
    const int l  = tid & 63;
    const int lr = l & 15;
    const int lg = l >> 4;
    const int swz = (lr & 7) << 4;

    #pragma unroll
    for (int q = 0; q < 4; ++q) {
        int bcol = q * 64 + l;
        bf16x8 v = *(const bf16x8*)(tepN + ((size_t)bcol * 128 + k) * 128 + jh * 64 + w * 8);
        #pragma unroll
        for (int r = 0; r < 8; ++r) {
            int j = w * 8 + r;
            int bo = (j * 512 + bcol * 2) ^ (r << 4);
            *(unsigned short*)((char*)tepS + bo) = ((unsigned short*)&v)[r];
        }
    }
    #pragma unroll
    for (int s = 0; s < 2; ++s)
        #pragma unroll
        for (int q = 0; q < 4; ++q) {
            int bcol = q * 64 + l;
            bf16x8 v = *(const bf16x8*)(hepN + ((size_t)bcol * 128 + k) * 128 + w * 16 + s * 8);
            #pragma unroll
            for (int r = 0; r < 8; ++r) {
                int i = w * 16 + s * 8 + r;
                int bo = (i * 512 + bcol * 2) ^ (r << 4);
                *(unsigned short*)((char*)hepS + bo) = ((unsigned short*)&v)[r];
            }
        }
    __syncthreads();

    bf16x8 ha[8];
    #pragma unroll
    for (int ks = 0; ks < 8; ++ks) {
        int ir = w * 16 + lr;
        int bo = (ir * 512 + (ks * 32 + lg * 8) * 2) ^ ((ir & 7) << 4);
        ha[ks] = *(const bf16x8*)((const char*)hepS + bo);
    }

    #pragma unroll 1
    for (int m = 0; m < NCLS; ++m) {
        {
            const unsigned short* tcm = TclsB + (size_t)m * (H2 * H2);
            f32x4 acc1[4][2];
            #pragma unroll
            for (int jt = 0; jt < 4; ++jt)
                #pragma unroll
                for (int ct = 0; ct < 2; ++ct) acc1[jt][ct] = (f32x4){0.f, 0.f, 0.f, 0.f};

            #pragma unroll
            for (int ks = 0; ks < 8; ++ks) {
                bf16x8 a[4], bb[2];
                #pragma unroll
                for (int jt = 0; jt < 4; ++jt) {
                    int byteoff = ((((jt * 16 + lr) << 8) + ks * 32 + lg * 8) << 1) ^ swz;
                    a[jt] = *(const bf16x8*)((const char*)tepS + byteoff);
                }
                #pragma unroll
                for (int ct = 0; ct < 2; ++ct)
                    bb[ct] = *(const bf16x8*)(tcm + (size_t)(w * 32 + ct * 16 + lr) * H2 + ks * 32 + lg * 8);
                #pragma unroll
                for (int jt = 0; jt < 4; ++jt)
                    #pragma unroll
                    for (int ct = 0; ct < 2; ++ct)
                        acc1[jt][ct] = __builtin_amdgcn_mfma_f32_16x16x32_bf16(a[jt], bb[ct], acc1[jt][ct], 0, 0, 0);
            }
            #pragma unroll
            for (int jt = 0; jt < 4; ++jt)
                #pragma unroll
                for (int ct = 0; ct < 2; ++ct)
                    #pragma unroll
                    for (int r = 0; r < 4; ++r) {
                        int j = jt * 16 + lg * 4 + r;
                        int c = w * 32 + ct * 16 + lr;
                        int byteoff = ((((j << 8) + c)) << 1) ^ ((j & 7) << 4);
                        *(unsigned short*)((char*)WS + byteoff) = f2bf(acc1[jt][ct][r]);
                    }
        }
        __syncthreads();

        {
            f32x4 acc2[4];
            #pragma unroll
            for (int jt = 0; jt < 4; ++jt) acc2[jt] = (f32x4){0.f, 0.f, 0.f, 0.f};

            #pragma unroll
            for (int ks = 0; ks < 8; ++ks) {
                #pragma unroll
                for (int jt = 0; jt < 4; ++jt) {
                    int byteoff = ((((jt * 16 + lr) << 8) + ks * 32 + lg * 8) << 1) ^ swz;
                    bf16x8 wb = *(const bf16x8*)((const char*)WS + byteoff);
                    acc2[jt] = __builtin_amdgcn_mfma_f32_16x16x32_bf16(ha[ks], wb, acc2[jt], 0, 0, 0);
                }
            }
            float* po = predT + (size_t)(k * NCLS + m) * (NENT * NENT);
            #pragma unroll
            for (int jt = 0; jt < 4; ++jt)
                #pragma unroll
                for (int r = 0; r < 4; ++r) {
                    int i = w * 16 + lg * 4 + r;
                    int j = jh * 64 + jt * 16 + lr;
                    po[i * NENT + j] = acc2[jt][r];
                }
        }
        __syncthreads();
    }
}

// ---------------- transpose: predT[km][ij] -> out[ij][km] ----------------
__global__ __launch_bounds__(256)
void transpose_out(const float* __restrict__ predT, float* __restrict__ out)
{
    __shared__ float Ls[160][33];
    const int bid = blockIdx.x;
    const int ij0 = (bid >> 2) * 32;
    const int km0 = (bid & 3) * 160;
    const int t = threadIdx.x;

    #pragma unroll
    for (int q = 0; q < 20; ++q) {
        int r = (t >> 5) + q * 8;
        int c = t & 31;
        Ls[r][c] = predT[(size_t)(km0 + r) * 16384 + ij0 + c];
    }
    __syncthreads();
    for (int idx = t; idx < 32 * 160; idx += 256) {
        int r = idx / 160, c = idx % 160;
        out[(size_t)(ij0 + r) * 640 + km0 + c] = Ls[c][r];
    }
}

extern "C" void kernel_launch(void* const* d_in, const int* in_sizes, int n_in,
                              void* d_out, int out_size, void* d_ws, size_t ws_size,
                              hipStream_t stream)
{
    (void)in_sizes; (void)n_in; (void)out_size; (void)ws_size;
    const float* enc  = (const float*)d_in[0];
    const int*   hidx = (const int*)d_in[1];
    const int*   tidx = (const int*)d_in[2];
    const int*   eidx = (const int*)d_in[3];
    const float* Whf = (const float*)d_in[4];
    const float* bhf = (const float*)d_in[5];
    const float* Whb = (const float*)d_in[6];
    const float* bhb = (const float*)d_in[7];
    const float* Wtf = (const float*)d_in[8];
    const float* btf = (const float*)d_in[9];
    const float* Wtb = (const float*)d_in[10];
    const float* btb = (const float*)d_in[11];
    const float* Wef = (const float*)d_in[12];
    const float* bef = (const float*)d_in[13];
    const float* Web = (const float*)d_in[14];
    const float* beb = (const float*)d_in[15];
    const float* T_he  = (const float*)d_in[16];
    const float* T_te  = (const float*)d_in[17];
    const float* T_cls = (const float*)d_in[18];

    float* out = (float*)d_out;
    char*  ws  = (char*)d_ws;
    unsigned short* poolB  = (unsigned short*)(ws + POOLB_OFF);
    unsigned short* hepN   = (unsigned short*)(ws + HEPB_OFF);
    unsigned short* tepN   = (unsigned short*)(ws + TEPB_OFF);
    unsigned short* TclsB  = (unsigned short*)(ws + TCLSB_OFF);
    unsigned short* WB     = (unsigned short*)(ws + WB_OFF);
    unsigned short* tokB   = (unsigned short*)(ws + TOKB_OFF);
    unsigned short* tmp30  = (unsigned short*)(ws + TMP30_OFF);
    unsigned short* tmp31  = (unsigned short*)(ws + TMP31_OFF);
    unsigned short* gatesB = (unsigned short*)(ws + GATESB_OFF);
    float*          predT  = (float*)(ws + PREDT_OFF);

    unsigned short* HeB = poolB;
    unsigned short* TeB = poolB + 1 * NENT * H2;
    unsigned short* EeB = poolB + 2 * NENT * H2;

    prep_kernel<<<7616, 256, 0, stream>>>(Whf, Whb, Wtf, Wtb, Wef, Web,
                                          T_cls, enc, hidx, tidx, eidx,
                                          WB, TclsB, tokB);

    gates_mfma<<<288, 256, 0, stream>>>(tokB, WB, gatesB);

    pool_epilogue<<<384, 256, 0, stream>>>(gatesB, bhf, bhb, btf, btb, bef, beb, poolB);

    p1_direct<<<2048, 256, 0, stream>>>(EeB, T_he, T_te, tmp30, tmp31);

    gemm2_mfma<<<512, 512, 0, stream>>>(HeB, TeB, tmp30, tmp31, hepN, tepN);

    step3_mfma<<<256, 512, 0, stream>>>(hepN, tepN, TclsB, predT);

    transpose_out<<<2048, 256, 0, stream>>>(predT, out);
}

// Round 17
// 168.672 us; speedup vs baseline: 1.0400x; 1.0400x over previous
//
#include <hip/hip_runtime.h>
#include <hip/hip_bf16.h>
#include <math.h>

#define DIM   768
#define HID   128
#define H2    256
#define NENT  128
#define SPAN  16
#define NCLS  5

// ---- ws layout (bytes); budget 75,890,688 proven by round-1 pass ----
// fixed: poolB @0 (196,608) | hepN @196,608 (8,388,608) | tepN @8,585,216 (8,388,608)
//        TclsB @16,973,824 (655,360)
// scratch S = ws+17,629,184:
//   WB    @S+0          (3,538,944)   K1-K2
//   tokB  @S+3,538,944  (9,437,184)   K1-K2
//   gatesB@S+12,976,128 (9,437,184)   K2-K3
//   tmp3  @S+0          (16,777,216)  K4-K5 (he), K6-K7 (te)  [over dead WB/tokB/gatesB-head]
//   TB    @S+22,413,312 (33,554,432)  K3-K6  [bf16 [b][a][c], one tensor at a time]
//   predT @S+0          (41,943,040)  K8-K9  [over dead tmp3/TB]
// peak = 17,629,184 + 55,967,744 = 73,596,928 <= 75,890,688 OK
#define POOLB_OFF  0
#define HEPB_OFF   196608
#define TEPB_OFF   (HEPB_OFF + 8388608)
#define TCLSB_OFF  (TEPB_OFF + 8388608)
#define S_OFF      17629184
#define WB_OFF     (S_OFF + 0)
#define TOKB_OFF   (S_OFF + 3538944)
#define GATESB_OFF (S_OFF + 12976128)
#define TMP3_OFF   (S_OFF + 0)
#define TB_OFF     (S_OFF + 22413312)
#define PREDT_OFF  (S_OFF + 0)

typedef __attribute__((ext_vector_type(8))) short bf16x8;
typedef __attribute__((ext_vector_type(4))) float f32x4;

__device__ __forceinline__ float sigmoidf_(float x) { return 1.0f / (1.0f + __expf(-x)); }

__device__ __forceinline__ unsigned short f2bf(float x) {
    __hip_bfloat16 h = __float2bfloat16(x);
    return *reinterpret_cast<unsigned short*>(&h);
}
__device__ __forceinline__ float bf2f(unsigned short u) {
    unsigned int v = ((unsigned int)u) << 16;
    float f; __builtin_memcpy(&f, &v, 4); return f;
}

// ---------------- prep: wconv + conv_tcls + gather_toks fused ----------------
__global__ __launch_bounds__(256)
void prep_kernel(const float* __restrict__ Whf, const float* __restrict__ Whb,
                 const float* __restrict__ Wtf, const float* __restrict__ Wtb,
                 const float* __restrict__ Wef, const float* __restrict__ Web,
                 const float* __restrict__ Tcls, const float* __restrict__ enc,
                 const int* __restrict__ idx_h, const int* __restrict__ idx_t,
                 const int* __restrict__ idx_e,
                 unsigned short* __restrict__ WB, unsigned short* __restrict__ TB,
                 unsigned short* __restrict__ tokB)
{
    const int bb = blockIdx.x;
    const int tid = threadIdx.x;
    if (bb < 1728) {
        int gid = bb * 256 + tid;                        // < 442368
        int t2  = gid / 73728;
        int rem = gid % 73728;
        int n   = rem / 192;
        int c4  = rem % 192;
        int gate = n >> 7, j = n & 127;
        int srow = (gate == 0) ? j : (gate == 1) ? 256 + j : 384 + j;
        const float* W = (t2 == 0) ? Whf : (t2 == 1) ? Whb : (t2 == 2) ? Wtf :
                         (t2 == 3) ? Wtb : (t2 == 4) ? Wef : Web;
        float4 v = ((const float4*)(W + srow * DIM))[c4];
        unsigned short* d = WB + ((size_t)(t2 * 384 + n)) * DIM + c4 * 4;
        d[0] = f2bf(v.x); d[1] = f2bf(v.y); d[2] = f2bf(v.z); d[3] = f2bf(v.w);
    } else if (bb < 3008) {
        int idx = (bb - 1728) * 256 + tid;               // < 327680
        int b = idx / (NCLS * H2);
        int r = idx % (NCLS * H2);
        int m = r >> 8, c = r & 255;
        TB[((m << 8) + c) * H2 + b] = f2bf(Tcls[idx]);
    } else {
        int gid = (bb - 3008) * 256 + tid;               // < 6144*192
        int r  = gid / 192, c4 = gid % 192;
        int type = r >> 11;
        int rem  = r & 2047;
        const int* idx = (type == 0) ? idx_h : (type == 1) ? idx_t : idx_e;
        int row = idx[rem];
        float4 v = ((const float4*)(enc + (size_t)row * DIM))[c4];
        unsigned short h4[4] = { f2bf(v.x), f2bf(v.y), f2bf(v.z), f2bf(v.w) };
        *(uint2*)(tokB + (size_t)r * DIM + c4 * 4) = *(uint2*)h4;
    }
}

// ---------------- gates GEMM (NT), LDS-staged 2-phase double-buffer; bf16 out ----------------
__global__ __launch_bounds__(256)
void gates_mfma(const unsigned short* __restrict__ tokB,
                const unsigned short* __restrict__ WB,
                unsigned short* __restrict__ gatesB)
{
    __shared__ unsigned short As[2][128 * 64];
    __shared__ unsigned short Bs[2][128 * 64];
    const int lbid = ((int)blockIdx.x & 7) * 36 + ((int)blockIdx.x >> 3);  // bijective
    const int type = lbid / 96;
    const int rem  = lbid % 96;
    const int mb0  = (rem / 6) * 128;
    const int nb0  = (rem % 6) * 128;
    const int tid = threadIdx.x;
    const int w = tid >> 6, l = tid & 63;
    const int lr = l & 15, lg = l >> 4;
    const unsigned short* A = tokB + (size_t)type * 2048 * DIM + (size_t)mb0 * DIM;
    const unsigned short* B = WB   + (size_t)type * 768  * DIM + (size_t)nb0 * DIM;

    const int sr0 = tid >> 3;
    const int sc  = tid & 7;

    bf16x8 ra[4], rb[4];
    #define LOADT(kt)                                                        \
        {                                                                    \
            const int koff = (kt) * 64 + sc * 8;                             \
            _Pragma("unroll")                                                \
            for (int p = 0; p < 4; ++p) {                                    \
                int rr = sr0 + p * 32;                                       \
                ra[p] = *(const bf16x8*)(A + (size_t)rr * DIM + koff);       \
                rb[p] = *(const bf16x8*)(B + (size_t)rr * DIM + koff);       \
            }                                                                \
        }
    #define WRITET(buf)                                                      \
        {                                                                    \
            _Pragma("unroll")                                                \
            for (int p = 0; p < 4; ++p) {                                    \
                int rr = sr0 + p * 32;                                       \
                int bo = (rr * 128 + sc * 16) ^ ((rr & 7) << 4);             \
                *(bf16x8*)((char*)As[buf] + bo) = ra[p];                     \
                *(bf16x8*)((char*)Bs[buf] + bo) = rb[p];                     \
            }                                                                \
        }

    f32x4 acc[4][4];
    #pragma unroll
    for (int mt = 0; mt < 4; ++mt)
        #pragma unroll
        for (int nt = 0; nt < 4; ++nt) acc[mt][nt] = (f32x4){0.f, 0.f, 0.f, 0.f};

    const int am0 = (w & 1) * 64;
    const int bn0 = (w >> 1) * 64;

    LOADT(0);
    WRITET(0);
    __syncthreads();

    int cur = 0;
    #pragma unroll 1
    for (int kt = 0; kt < 12; ++kt) {
        if (kt + 1 < 12) LOADT(kt + 1);

        #pragma unroll
        for (int ks = 0; ks < 2; ++ks) {
            bf16x8 af[4], bf[4];
            #pragma unroll
            for (int mt = 0; mt < 4; ++mt) {
                int rr = am0 + mt * 16 + lr;
                int bo = (rr * 128 + ks * 64 + lg * 16) ^ ((rr & 7) << 4);
                af[mt] = *(const bf16x8*)((const char*)As[cur] + bo);
            }
            #pragma unroll
            for (int nt = 0; nt < 4; ++nt) {
                int rr = bn0 + nt * 16 + lr;
                int bo = (rr * 128 + ks * 64 + lg * 16) ^ ((rr & 7) << 4);
                bf[nt] = *(const bf16x8*)((const char*)Bs[cur] + bo);
            }
            #pragma unroll
            for (int mt = 0; mt < 4; ++mt)
                #pragma unroll
                for (int nt = 0; nt < 4; ++nt)
                    acc[mt][nt] = __builtin_amdgcn_mfma_f32_16x16x32_bf16(af[mt], bf[nt], acc[mt][nt], 0, 0, 0);
        }

        if (kt + 1 < 12) {
            WRITET(cur ^ 1);
        }
        __syncthreads();
        cur ^= 1;
    }
    #undef LOADT
    #undef WRITET

    unsigned short* C = gatesB + (size_t)type * 2048 * 768 + (size_t)mb0 * 768 + nb0;
    #pragma unroll
    for (int mt = 0; mt < 4; ++mt)
        #pragma unroll
        for (int nt = 0; nt < 4; ++nt)
            #pragma unroll
            for (int r = 0; r < 4; ++r)
                C[(size_t)(am0 + mt * 16 + lg * 4 + r) * 768 + bn0 + nt * 16 + lr] = f2bf(acc[mt][nt][r]);
}

// ---------------- poolconv: pool epilogue (384 blocks) U convT T_he->TB (512 blocks x16) ----
__global__ __launch_bounds__(256)
void poolconv(const unsigned short* __restrict__ gatesB,
              const float* __restrict__ bhf, const float* __restrict__ bhb,
              const float* __restrict__ btf, const float* __restrict__ btb,
              const float* __restrict__ bef, const float* __restrict__ beb,
              unsigned short* __restrict__ poolB,
              const float* __restrict__ T0, unsigned short* __restrict__ TB)
{
    const int bb = blockIdx.x;
    const int tid = threadIdx.x;
    if (bb < 384) {
        const int type = bb >> 7;
        const int ent  = bb & 127;
        const int dir  = tid >> 7;
        const int j    = tid & 127;
        const float* Bv = (type == 0) ? (dir ? bhb : bhf)
                        : (type == 1) ? (dir ? btb : btf)
                                      : (dir ? beb : bef);
        const float bi = Bv[j], bg = Bv[2 * HID + j], bo = Bv[3 * HID + j];
        const unsigned short* g0 = gatesB + ((size_t)type * 2048 + ent * 16) * 768 + dir * 384 + j;
        float hmax = -1e30f;
        #pragma unroll
        for (int ll = 0; ll < SPAN; ++ll) {
            const unsigned short* gr = g0 + ll * 768;
            float iv = sigmoidf_(bf2f(gr[0])   + bi);
            float gv = tanhf(   bf2f(gr[128]) + bg);
            float ov = sigmoidf_(bf2f(gr[256]) + bo);
            hmax = fmaxf(hmax, ov * tanhf(iv * gv));
        }
        poolB[(size_t)(type * NENT + ent) * H2 + dir * HID + j] = f2bf(hmax);
    } else {
        // convT: 2,097,152 units of 32B fp32 -> 16B bf16; sequential read, b-major scatter write
        int W0 = (bb - 384) * 256 + tid;                 // < 131072
        #pragma unroll 1
        for (int it = 0; it < 16; ++it) {
            int idx = W0 + it * 131072;
            int a  = idx >> 13;
            int rr = idx & 8191;
            int b  = rr >> 5;
            int c8 = rr & 31;
            const float* src = T0 + ((size_t)(a * 256 + b) << 8) + c8 * 8;
            float4 v0 = ((const float4*)src)[0];
            float4 v1 = ((const float4*)src)[1];
            bf16x8 hv; unsigned short* hp = (unsigned short*)&hv;
            hp[0]=f2bf(v0.x); hp[1]=f2bf(v0.y); hp[2]=f2bf(v0.z); hp[3]=f2bf(v0.w);
            hp[4]=f2bf(v1.x); hp[5]=f2bf(v1.y); hp[6]=f2bf(v1.z); hp[7]=f2bf(v1.w);
            *(bf16x8*)(TB + (((size_t)(b * 256 + a)) << 8) + c8 * 8) = hv;
        }
    }
}

// ---------------- p1tb: gemm2-clone reading bf16 TB -- W[a][k]=sum_c TB[b][a][c]*Ee[k][c] ----
// grid 512 = b(256) x ah(2); 512 thr = 8 waves (aw 2 x kw 4); LDS 64KB slab [128a][256c] swz.
// Stage = 8 independent bf16x8 loads/thread from a CONTIGUOUS 64KB block (proven-fast shape).
__global__ __launch_bounds__(512)
void p1tb(const unsigned short* __restrict__ EeB,
          const unsigned short* __restrict__ TB,   // [256b][256a][256c] bf16
          unsigned short* __restrict__ tmp3)       // [256b][256a][128k] bf16
{
    __shared__ __align__(16) char smem[65536];
    const int bid = blockIdx.x;
    const int b  = bid >> 1;
    const int ah = bid & 1;
    const unsigned short* src = TB + (((size_t)b * 256 + ah * 128) << 8);  // 64KB contiguous
    const int tid = threadIdx.x;
    const int w = tid >> 6, l = tid & 63;
    const int lr = l & 15, lg = l >> 4;

    // ---- stage: 4096 chunks of 16B; iteration it covers contiguous 8KB
    #pragma unroll
    for (int it = 0; it < 8; ++it) {
        int L = it * 512 + tid;
        int row = L >> 5, ch = L & 31;
        bf16x8 v = *(const bf16x8*)(src + (size_t)L * 8);
        int bo = (row * 512 + ch * 16) ^ ((row & 7) << 4);
        *(bf16x8*)(smem + bo) = v;
    }
    __syncthreads();

    // ---- GEMM: M=128 a, N=128 k, K=256 c; wave tile 64a x 32k
    const int aw = (w & 1) * 64;
    const int kw = (w >> 1) * 32;
    f32x4 acc[4][2];
    #pragma unroll
    for (int mt = 0; mt < 4; ++mt)
        #pragma unroll
        for (int nt = 0; nt < 2; ++nt) acc[mt][nt] = (f32x4){0.f, 0.f, 0.f, 0.f};

    #pragma unroll
    for (int ks = 0; ks < 8; ++ks) {
        bf16x8 af[4], bf[2];
        #pragma unroll
        for (int mt = 0; mt < 4; ++mt) {
            int row = aw + mt * 16 + lr;
            int bo = (row * 512 + ks * 64 + lg * 16) ^ ((row & 7) << 4);
            af[mt] = *(const bf16x8*)(smem + bo);
        }
        #pragma unroll
        for (int nt = 0; nt < 2; ++nt)
            bf[nt] = *(const bf16x8*)(EeB + (kw + nt * 16 + lr) * H2 + ks * 32 + lg * 8);
        #pragma unroll
        for (int mt = 0; mt < 4; ++mt)
            #pragma unroll
            for (int nt = 0; nt < 2; ++nt)
                acc[mt][nt] = __builtin_amdgcn_mfma_f32_16x16x32_bf16(af[mt], bf[nt], acc[mt][nt], 0, 0, 0);
    }

    // ---- write tmp3[b][a][k]
    #pragma unroll
    for (int mt = 0; mt < 4; ++mt)
        #pragma unroll
        for (int nt = 0; nt < 2; ++nt)
            #pragma unroll
            for (int r = 0; r < 4; ++r) {
                int a_ = ah * 128 + aw + mt * 16 + lg * 4 + r;
                int k_ = kw + nt * 16 + lr;
                tmp3[((size_t)b * 256 + a_) * 128 + k_] = f2bf(acc[mt][nt][r]);
            }
}

// ---------------- g2conv: gemm2s (256 blocks) U convT T_te->TB (512 blocks x8, 512thr) ----
// gemm2s: out[b][k][i] = sum_a tmp3[b][a][k] * Hx[i][a]
__global__ __launch_bounds__(512)
void g2conv(const unsigned short* __restrict__ Hx,
            const unsigned short* __restrict__ tmp3,
            unsigned short* __restrict__ outp,     // [256b][128k][128i]
            const float* __restrict__ T1,          // may be null (no conv part)
            unsigned short* __restrict__ TB)
{
    const int bb = blockIdx.x;
    const int tid = threadIdx.x;
    if (bb >= 256) {
        // convT for T_te: 512 blocks x 512 thr x 8 iters x 32B = 64MB
        int W0 = (bb - 256) * 512 + tid;                 // < 262144
        #pragma unroll 1
        for (int it = 0; it < 8; ++it) {
            int idx = W0 + it * 262144;
            int a  = idx >> 13;
            int rr = idx & 8191;
            int b  = rr >> 5;
            int c8 = rr & 31;
            const float* src = T1 + ((size_t)(a * 256 + b) << 8) + c8 * 8;
            float4 v0 = ((const float4*)src)[0];
            float4 v1 = ((const float4*)src)[1];
            bf16x8 hv; unsigned short* hp = (unsigned short*)&hv;
            hp[0]=f2bf(v0.x); hp[1]=f2bf(v0.y); hp[2]=f2bf(v0.z); hp[3]=f2bf(v0.w);
            hp[4]=f2bf(v1.x); hp[5]=f2bf(v1.y); hp[6]=f2bf(v1.z); hp[7]=f2bf(v1.w);
            *(bf16x8*)(TB + (((size_t)(b * 256 + a)) << 8) + c8 * 8) = hv;
        }
        return;
    }
    __shared__ unsigned short WT[128 * 256];
    const int b = bb;
    const unsigned short* src = tmp3 + (size_t)b * 32768;
    unsigned short* po = outp + (size_t)b * 16384;
    const int w = tid >> 6, l = tid & 63;
    const int lr = l & 15, lg = l >> 4;

    // ---- transpose-stage [256a][128k] -> WT[k][a] swz
    {
        const int a0 = tid >> 4;
        const int k8 = (tid & 15) * 8;
        #pragma unroll
        for (int it = 0; it < 8; ++it) {
            int aa = it * 32 + a0;
            bf16x8 v = *(const bf16x8*)(src + aa * 128 + k8);
            #pragma unroll
            for (int j = 0; j < 8; ++j) {
                int kk = k8 + j;                       // kk&7 == j
                int bo = (kk * 512 + aa * 2) ^ (j << 4);
                *(unsigned short*)((char*)WT + bo) = ((unsigned short*)&v)[j];
            }
        }
    }
    __syncthreads();

    // ---- GEMM: M=128 k, N=128 i, K=256 a
    const int kw = (w & 1) * 64;
    const int iw = (w >> 1) * 32;
    f32x4 acc[4][2];
    #pragma unroll
    for (int mt = 0; mt < 4; ++mt)
        #pragma unroll
        for (int nt = 0; nt < 2; ++nt) acc[mt][nt] = (f32x4){0.f, 0.f, 0.f, 0.f};

    #pragma unroll
    for (int ks = 0; ks < 8; ++ks) {
        bf16x8 af[4], bf[2];
        #pragma unroll
        for (int mt = 0; mt < 4; ++mt) {
            int kr = kw + mt * 16 + lr;
            int bo = (kr * 512 + (ks * 32 + lg * 8) * 2) ^ ((kr & 7) << 4);
            af[mt] = *(const bf16x8*)((const char*)WT + bo);
        }
        #pragma unroll
        for (int nt = 0; nt < 2; ++nt)
            bf[nt] = *(const bf16x8*)(Hx + (iw + nt * 16 + lr) * H2 + ks * 32 + lg * 8);
        #pragma unroll
        for (int mt = 0; mt < 4; ++mt)
            #pragma unroll
            for (int nt = 0; nt < 2; ++nt)
                acc[mt][nt] = __builtin_amdgcn_mfma_f32_16x16x32_bf16(af[mt], bf[nt], acc[mt][nt], 0, 0, 0);
    }
    #pragma unroll
    for (int mt = 0; mt < 4; ++mt)
        #pragma unroll
        for (int nt = 0; nt < 2; ++nt)
            #pragma unroll
            for (int r = 0; r < 4; ++r) {
                int k_ = kw + mt * 16 + lg * 4 + r;
                int i_ = iw + nt * 16 + lr;
                po[k_ * 128 + i_] = f2bf(acc[mt][nt][r]);
            }
}

// ---------------- step3: block per (k, j-half); m-loop inside ----------------
__global__ __launch_bounds__(512)
void step3_mfma(const unsigned short* __restrict__ hepN,  // [256 beta][128 k][128 i]
                const unsigned short* __restrict__ tepN,  // [256 b][128 k][128 j]
                const unsigned short* __restrict__ TclsB, // [m][c][b]
                float* __restrict__ predT)
{
    __shared__ unsigned short hepS[128 * 256];
    __shared__ unsigned short tepS[64 * 256];
    __shared__ unsigned short WS[64 * 256];
    const int lbid = (blockIdx.x & 7) * 32 + (blockIdx.x >> 3);
    const int k  = lbid >> 1;
    const int jh = lbid & 1;
    const int tid = threadIdx.x;
    const int w  = tid >> 6;
    const int l  = tid & 63;
    const int lr = l & 15;
    const int lg = l >> 4;
    const int swz = (lr & 7) << 4;

    #pragma unroll
    for (int q = 0; q < 4; ++q) {
        int bcol = q * 64 + l;
        bf16x8 v = *(const bf16x8*)(tepN + ((size_t)bcol * 128 + k) * 128 + jh * 64 + w * 8);
        #pragma unroll
        for (int r = 0; r < 8; ++r) {
            int j = w * 8 + r;
            int bo = (j * 512 + bcol * 2) ^ (r << 4);
            *(unsigned short*)((char*)tepS + bo) = ((unsigned short*)&v)[r];
        }
    }
    #pragma unroll
    for (int s = 0; s < 2; ++s)
        #pragma unroll
        for (int q = 0; q < 4; ++q) {
            int bcol = q * 64 + l;
            bf16x8 v = *(const bf16x8*)(hepN + ((size_t)bcol * 128 + k) * 128 + w * 16 + s * 8);
            #pragma unroll
            for (int r = 0; r < 8; ++r) {
                int i = w * 16 + s * 8 + r;
                int bo = (i * 512 + bcol * 2) ^ (r << 4);
                *(unsigned short*)((char*)hepS + bo) = ((unsigned short*)&v)[r];
            }
        }
    __syncthreads();

    bf16x8 ha[8];
    #pragma unroll
    for (int ks = 0; ks < 8; ++ks) {
        int ir = w * 16 + lr;
        int bo = (ir * 512 + (ks * 32 + lg * 8) * 2) ^ ((ir & 7) << 4);
        ha[ks] = *(const bf16x8*)((const char*)hepS + bo);
    }

    #pragma unroll 1
    for (int m = 0; m < NCLS; ++m) {
        {
            const unsigned short* tcm = TclsB + (size_t)m * (H2 * H2);
            f32x4 acc1[4][2];
            #pragma unroll
            for (int jt = 0; jt < 4; ++jt)
                #pragma unroll
                for (int ct = 0; ct < 2; ++ct) acc1[jt][ct] = (f32x4){0.f, 0.f, 0.f, 0.f};

            #pragma unroll
            for (int ks = 0; ks < 8; ++ks) {
                bf16x8 a[4], bb[2];
                #pragma unroll
                for (int jt = 0; jt < 4; ++jt) {
                    int byteoff = ((((jt * 16 + lr) << 8) + ks * 32 + lg * 8) << 1) ^ swz;
                    a[jt] = *(const bf16x8*)((const char*)tepS + byteoff);
                }
                #pragma unroll
                for (int ct = 0; ct < 2; ++ct)
                    bb[ct] = *(const bf16x8*)(tcm + (size_t)(w * 32 + ct * 16 + lr) * H2 + ks * 32 + lg * 8);
                #pragma unroll
                for (int jt = 0; jt < 4; ++jt)
                    #pragma unroll
                    for (int ct = 0; ct < 2; ++ct)
                        acc1[jt][ct] = __builtin_amdgcn_mfma_f32_16x16x32_bf16(a[jt], bb[ct], acc1[jt][ct], 0, 0, 0);
            }
            #pragma unroll
            for (int jt = 0; jt < 4; ++jt)
                #pragma unroll
                for (int ct = 0; ct < 2; ++ct)
                    #pragma unroll
                    for (int r = 0; r < 4; ++r) {
                        int j = jt * 16 + lg * 4 + r;
                        int c = w * 32 + ct * 16 + lr;
                        int byteoff = ((((j << 8) + c)) << 1) ^ ((j & 7) << 4);
                        *(unsigned short*)((char*)WS + byteoff) = f2bf(acc1[jt][ct][r]);
                    }
        }
        __syncthreads();

        {
            f32x4 acc2[4];
            #pragma unroll
            for (int jt = 0; jt < 4; ++jt) acc2[jt] = (f32x4){0.f, 0.f, 0.f, 0.f};

            #pragma unroll
            for (int ks = 0; ks < 8; ++ks) {
                #pragma unroll
                for (int jt = 0; jt < 4; ++jt) {
                    int byteoff = ((((jt * 16 + lr) << 8) + ks * 32 + lg * 8) << 1) ^ swz;
                    bf16x8 wb = *(const bf16x8*)((const char*)WS + byteoff);
                    acc2[jt] = __builtin_amdgcn_mfma_f32_16x16x32_bf16(ha[ks], wb, acc2[jt], 0, 0, 0);
                }
            }
            float* po = predT + (size_t)(k * NCLS + m) * (NENT * NENT);
            #pragma unroll
            for (int jt = 0; jt < 4; ++jt)
                #pragma unroll
                for (int r = 0; r < 4; ++r) {
                    int i = w * 16 + lg * 4 + r;
                    int j = jh * 64 + jt * 16 + lr;
                    po[i * NENT + j] = acc2[jt][r];
                }
        }
        __syncthreads();
    }
}

// ---------------- transpose: predT[km][ij] -> out[ij][km] ----------------
__global__ __launch_bounds__(256)
void transpose_out(const float* __restrict__ predT, float* __restrict__ out)
{
    __shared__ float Ls[160][33];
    const int bid = blockIdx.x;
    const int ij0 = (bid >> 2) * 32;
    const int km0 = (bid & 3) * 160;
    const int t = threadIdx.x;

    #pragma unroll
    for (int q = 0; q < 20; ++q) {
        int r = (t >> 5) + q * 8;
        int c = t & 31;
        Ls[r][c] = predT[(size_t)(km0 + r) * 16384 + ij0 + c];
    }
    __syncthreads();
    for (int idx = t; idx < 32 * 160; idx += 256) {
        int r = idx / 160, c = idx % 160;
        out[(size_t)(ij0 + r) * 640 + km0 + c] = Ls[c][r];
    }
}

extern "C" void kernel_launch(void* const* d_in, const int* in_sizes, int n_in,
                              void* d_out, int out_size, void* d_ws, size_t ws_size,
                              hipStream_t stream)
{
    (void)in_sizes; (void)n_in; (void)out_size; (void)ws_size;
    const float* enc  = (const float*)d_in[0];
    const int*   hidx = (const int*)d_in[1];
    const int*   tidx = (const int*)d_in[2];
    const int*   eidx = (const int*)d_in[3];
    const float* Whf = (const float*)d_in[4];
    const float* bhf = (const float*)d_in[5];
    const float* Whb = (const float*)d_in[6];
    const float* bhb = (const float*)d_in[7];
    const float* Wtf = (const float*)d_in[8];
    const float* btf = (const float*)d_in[9];
    const float* Wtb = (const float*)d_in[10];
    const float* btb = (const float*)d_in[11];
    const float* Wef = (const float*)d_in[12];
    const float* bef = (const float*)d_in[13];
    const float* Web = (const float*)d_in[14];
    const float* beb = (const float*)d_in[15];
    const float* T_he  = (const float*)d_in[16];
    const float* T_te  = (const float*)d_in[17];
    const float* T_cls = (const float*)d_in[18];

    float* out = (float*)d_out;
    char*  ws  = (char*)d_ws;
    unsigned short* poolB  = (unsigned short*)(ws + POOLB_OFF);
    unsigned short* hepN   = (unsigned short*)(ws + HEPB_OFF);
    unsigned short* tepN   = (unsigned short*)(ws + TEPB_OFF);
    unsigned short* TclsB  = (unsigned short*)(ws + TCLSB_OFF);
    unsigned short* WB     = (unsigned short*)(ws + WB_OFF);
    unsigned short* tokB   = (unsigned short*)(ws + TOKB_OFF);
    unsigned short* gatesB = (unsigned short*)(ws + GATESB_OFF);
    unsigned short* tmp3   = (unsigned short*)(ws + TMP3_OFF);
    unsigned short* TB     = (unsigned short*)(ws + TB_OFF);
    float*          predT  = (float*)(ws + PREDT_OFF);

    unsigned short* HeB = poolB;
    unsigned short* TeB = poolB + 1 * NENT * H2;
    unsigned short* EeB = poolB + 2 * NENT * H2;

    prep_kernel<<<7616, 256, 0, stream>>>(Whf, Whb, Wtf, Wtb, Wef, Web,
                                          T_cls, enc, hidx, tidx, eidx,
                                          WB, TclsB, tokB);

    gates_mfma<<<288, 256, 0, stream>>>(tokB, WB, gatesB);

    // K3: pool epilogue || convert T_he -> TB
    poolconv<<<896, 256, 0, stream>>>(gatesB, bhf, bhb, btf, btb, bef, beb,
                                      poolB, T_he, TB);

    // K4: P1 for T_he
    p1tb<<<512, 512, 0, stream>>>(EeB, TB, tmp3);

    // K5: gemm2 (he) || convert T_te -> TB
    g2conv<<<768, 512, 0, stream>>>(HeB, tmp3, hepN, T_te, TB);

    // K6: P1 for T_te
    p1tb<<<512, 512, 0, stream>>>(EeB, TB, tmp3);

    // K7: gemm2 (te) only
    g2conv<<<256, 512, 0, stream>>>(TeB, tmp3, tepN, (const float*)nullptr, TB);

    step3_mfma<<<256, 512, 0, stream>>>(hepN, tepN, TclsB, predT);

    transpose_out<<<2048, 256, 0, stream>>>(predT, out);
}

// Round 18
// 152.569 us; speedup vs baseline: 1.1497x; 1.1055x over previous
//
#include <hip/hip_runtime.h>
#include <hip/hip_bf16.h>
#include <math.h>

#define DIM   768
#define HID   128
#define H2    256
#define NENT  128
#define SPAN  16
#define NCLS  5

// ---- ws layout (bytes); peak 72,548,352 <= 73,596,928 proven by r17 pass ----
// poolB  @0          (196,608)                     K3-K4
// TclsB  @196,608    (655,360)                     K1-K6
// hepT   @851,968    (8,388,608)  [k][i][c]        K5-K6
// tepT   @9,240,576  (8,388,608)  [k][j][b]        K5-K6
// hepN   @17,629,184 (8,388,608)  [b][k][i]        K4-K5 (dead after trT)
// tepN   @26,017,792 (8,388,608)                   K4-K5 (dead after trT)
// gatesB @17,629,184 (9,437,184)                   K2-K3 (dead before hepN)
// predT  @17,629,184 (41,943,040)                  K6-K7 (over dead hepN/tepN)
// WB     @59,572,224 (3,538,944)                   K1-K2
// tokB   @63,111,168 (9,437,184)  ends 72,548,352  K1-K2
#define POOLB_OFF  0
#define TCLSB_OFF  196608
#define HEPT_OFF   851968
#define TEPT_OFF   9240576
#define HEPN_OFF   17629184
#define TEPN_OFF   26017792
#define GATESB_OFF 17629184
#define PREDT_OFF  17629184
#define WB_OFF     59572224
#define TOKB_OFF   63111168

typedef __attribute__((ext_vector_type(8))) short bf16x8;
typedef __attribute__((ext_vector_type(4))) float f32x4;

__device__ __forceinline__ float sigmoidf_(float x) { return 1.0f / (1.0f + __expf(-x)); }

__device__ __forceinline__ unsigned short f2bf(float x) {
    __hip_bfloat16 h = __float2bfloat16(x);
    return *reinterpret_cast<unsigned short*>(&h);
}
__device__ __forceinline__ float bf2f(unsigned short u) {
    unsigned int v = ((unsigned int)u) << 16;
    float f; __builtin_memcpy(&f, &v, 4); return f;
}

// ---------------- prep: wconv + conv_tcls + gather_toks fused ----------------
__global__ __launch_bounds__(256)
void prep_kernel(const float* __restrict__ Whf, const float* __restrict__ Whb,
                 const float* __restrict__ Wtf, const float* __restrict__ Wtb,
                 const float* __restrict__ Wef, const float* __restrict__ Web,
                 const float* __restrict__ Tcls, const float* __restrict__ enc,
                 const int* __restrict__ idx_h, const int* __restrict__ idx_t,
                 const int* __restrict__ idx_e,
                 unsigned short* __restrict__ WB, unsigned short* __restrict__ TB,
                 unsigned short* __restrict__ tokB)
{
    const int bb = blockIdx.x;
    const int tid = threadIdx.x;
    if (bb < 1728) {
        int gid = bb * 256 + tid;                        // < 442368
        int t2  = gid / 73728;
        int rem = gid % 73728;
        int n   = rem / 192;
        int c4  = rem % 192;
        int gate = n >> 7, j = n & 127;
        int srow = (gate == 0) ? j : (gate == 1) ? 256 + j : 384 + j;
        const float* W = (t2 == 0) ? Whf : (t2 == 1) ? Whb : (t2 == 2) ? Wtf :
                         (t2 == 3) ? Wtb : (t2 == 4) ? Wef : Web;
        float4 v = ((const float4*)(W + srow * DIM))[c4];
        unsigned short* d = WB + ((size_t)(t2 * 384 + n)) * DIM + c4 * 4;
        d[0] = f2bf(v.x); d[1] = f2bf(v.y); d[2] = f2bf(v.z); d[3] = f2bf(v.w);
    } else if (bb < 3008) {
        int idx = (bb - 1728) * 256 + tid;               // < 327680
        int b = idx / (NCLS * H2);
        int r = idx % (NCLS * H2);
        int m = r >> 8, c = r & 255;
        TB[((m << 8) + c) * H2 + b] = f2bf(Tcls[idx]);
    } else {
        int gid = (bb - 3008) * 256 + tid;               // < 6144*192
        int r  = gid / 192, c4 = gid % 192;
        int type = r >> 11;
        int rem  = r & 2047;
        const int* idx = (type == 0) ? idx_h : (type == 1) ? idx_t : idx_e;
        int row = idx[rem];
        float4 v = ((const float4*)(enc + (size_t)row * DIM))[c4];
        unsigned short h4[4] = { f2bf(v.x), f2bf(v.y), f2bf(v.z), f2bf(v.w) };
        *(uint2*)(tokB + (size_t)r * DIM + c4 * 4) = *(uint2*)h4;
    }
}

// ---------------- gates GEMM (NT), LDS-staged 2-phase double-buffer; bf16 out ----------------
__global__ __launch_bounds__(256)
void gates_mfma(const unsigned short* __restrict__ tokB,
                const unsigned short* __restrict__ WB,
                unsigned short* __restrict__ gatesB)
{
    __shared__ unsigned short As[2][128 * 64];
    __shared__ unsigned short Bs[2][128 * 64];
    const int lbid = ((int)blockIdx.x & 7) * 36 + ((int)blockIdx.x >> 3);  // bijective
    const int type = lbid / 96;
    const int rem  = lbid % 96;
    const int mb0  = (rem / 6) * 128;
    const int nb0  = (rem % 6) * 128;
    const int tid = threadIdx.x;
    const int w = tid >> 6, l = tid & 63;
    const int lr = l & 15, lg = l >> 4;
    const unsigned short* A = tokB + (size_t)type * 2048 * DIM + (size_t)mb0 * DIM;
    const unsigned short* B = WB   + (size_t)type * 768  * DIM + (size_t)nb0 * DIM;

    const int sr0 = tid >> 3;
    const int sc  = tid & 7;

    bf16x8 ra[4], rb[4];
    #define LOADT(kt)                                                        \
        {                                                                    \
            const int koff = (kt) * 64 + sc * 8;                             \
            _Pragma("unroll")                                                \
            for (int p = 0; p < 4; ++p) {                                    \
                int rr = sr0 + p * 32;                                       \
                ra[p] = *(const bf16x8*)(A + (size_t)rr * DIM + koff);       \
                rb[p] = *(const bf16x8*)(B + (size_t)rr * DIM + koff);       \
            }                                                                \
        }
    #define WRITET(buf)                                                      \
        {                                                                    \
            _Pragma("unroll")                                                \
            for (int p = 0; p < 4; ++p) {                                    \
                int rr = sr0 + p * 32;                                       \
                int bo = (rr * 128 + sc * 16) ^ ((rr & 7) << 4);             \
                *(bf16x8*)((char*)As[buf] + bo) = ra[p];                     \
                *(bf16x8*)((char*)Bs[buf] + bo) = rb[p];                     \
            }                                                                \
        }

    f32x4 acc[4][4];
    #pragma unroll
    for (int mt = 0; mt < 4; ++mt)
        #pragma unroll
        for (int nt = 0; nt < 4; ++nt) acc[mt][nt] = (f32x4){0.f, 0.f, 0.f, 0.f};

    const int am0 = (w & 1) * 64;
    const int bn0 = (w >> 1) * 64;

    LOADT(0);
    WRITET(0);
    __syncthreads();

    int cur = 0;
    #pragma unroll 1
    for (int kt = 0; kt < 12; ++kt) {
        if (kt + 1 < 12) LOADT(kt + 1);

        #pragma unroll
        for (int ks = 0; ks < 2; ++ks) {
            bf16x8 af[4], bf[4];
            #pragma unroll
            for (int mt = 0; mt < 4; ++mt) {
                int rr = am0 + mt * 16 + lr;
                int bo = (rr * 128 + ks * 64 + lg * 16) ^ ((rr & 7) << 4);
                af[mt] = *(const bf16x8*)((const char*)As[cur] + bo);
            }
            #pragma unroll
            for (int nt = 0; nt < 4; ++nt) {
                int rr = bn0 + nt * 16 + lr;
                int bo = (rr * 128 + ks * 64 + lg * 16) ^ ((rr & 7) << 4);
                bf[nt] = *(const bf16x8*)((const char*)Bs[cur] + bo);
            }
            #pragma unroll
            for (int mt = 0; mt < 4; ++mt)
                #pragma unroll
                for (int nt = 0; nt < 4; ++nt)
                    acc[mt][nt] = __builtin_amdgcn_mfma_f32_16x16x32_bf16(af[mt], bf[nt], acc[mt][nt], 0, 0, 0);
        }

        if (kt + 1 < 12) {
            WRITET(cur ^ 1);
        }
        __syncthreads();
        cur ^= 1;
    }
    #undef LOADT
    #undef WRITET

    unsigned short* C = gatesB + (size_t)type * 2048 * 768 + (size_t)mb0 * 768 + nb0;
    #pragma unroll
    for (int mt = 0; mt < 4; ++mt)
        #pragma unroll
        for (int nt = 0; nt < 4; ++nt)
            #pragma unroll
            for (int r = 0; r < 4; ++r)
                C[(size_t)(am0 + mt * 16 + lg * 4 + r) * 768 + bn0 + nt * 16 + lr] = f2bf(acc[mt][nt][r]);
}

// ---------------- pool epilogue (bf16 gates) ----------------
__global__ __launch_bounds__(256)
void pool_epilogue(const unsigned short* __restrict__ gatesB,
                   const float* __restrict__ bhf, const float* __restrict__ bhb,
                   const float* __restrict__ btf, const float* __restrict__ btb,
                   const float* __restrict__ bef, const float* __restrict__ beb,
                   unsigned short* __restrict__ poolB)
{
    const int type = blockIdx.x >> 7;
    const int ent  = blockIdx.x & 127;
    const int tid  = threadIdx.x;
    const int dir  = tid >> 7;
    const int j    = tid & 127;
    const float* Bv = (type == 0) ? (dir ? bhb : bhf)
                    : (type == 1) ? (dir ? btb : btf)
                                  : (dir ? beb : bef);
    const float bi = Bv[j], bg = Bv[2 * HID + j], bo = Bv[3 * HID + j];
    const unsigned short* g0 = gatesB + ((size_t)type * 2048 + ent * 16) * 768 + dir * 384 + j;
    float hmax = -1e30f;
    #pragma unroll
    for (int ll = 0; ll < SPAN; ++ll) {
        const unsigned short* gr = g0 + ll * 768;
        float iv = sigmoidf_(bf2f(gr[0])   + bi);
        float gv = tanhf(   bf2f(gr[128]) + bg);
        float ov = sigmoidf_(bf2f(gr[256]) + bo);
        hmax = fmaxf(hmax, ov * tanhf(iv * gv));
    }
    poolB[(size_t)(type * NENT + ent) * H2 + dir * HID + j] = f2bf(hmax);
}

// ---------------- pair: fused gemm1+gemm2 (r11 best-measured T-path) ----------------
__global__ __launch_bounds__(1024)
void pair_mfma(const unsigned short* __restrict__ EeB,
               const unsigned short* __restrict__ HeB,
               const unsigned short* __restrict__ TeB,
               const float* __restrict__ T0, const float* __restrict__ T1,
               unsigned short* __restrict__ hepN,   // [256 b][128 k][128 i]
               unsigned short* __restrict__ tepN)
{
    __shared__ __align__(16) char smem[131072];
    const int bid = blockIdx.x;
    const int t = bid >> 8;
    const int b = bid & 255;
    const float* T = t ? T1 : T0;
    const unsigned short* Hx = t ? TeB : HeB;
    unsigned short* outp = t ? tepN : hepN;
    const int tid = threadIdx.x;
    const int w = tid >> 6, l = tid & 63;
    const int lr = l & 15, lg = l >> 4;

    // ---- stage T[:,b,:] fp32 -> slab bf16 swz (conflict-free mapping)
    {
        const int r0 = tid >> 5;
        const int ch = tid & 31;
        #pragma unroll
        for (int p = 0; p < 8; ++p) {
            int row = p * 32 + r0;
            const float* src = T + ((size_t)row * 256 + b) * 256 + ch * 8;
            float4 v0 = ((const float4*)src)[0];
            float4 v1 = ((const float4*)src)[1];
            bf16x8 hv; unsigned short* hp = (unsigned short*)&hv;
            hp[0]=f2bf(v0.x); hp[1]=f2bf(v0.y); hp[2]=f2bf(v0.z); hp[3]=f2bf(v0.w);
            hp[4]=f2bf(v1.x); hp[5]=f2bf(v1.y); hp[6]=f2bf(v1.z); hp[7]=f2bf(v1.w);
            int bo = (row * 512 + ch * 16) ^ ((row & 7) << 4);
            *(bf16x8*)(smem + bo) = hv;
        }
    }
    __syncthreads();

    // ---- P1: W[a][k]; 16 waves: aw = w&3 (64a), kw = w>>2 (32k)
    f32x4 acc1[4][2];
    {
        const int aw = (w & 3) * 64;
        const int kw = (w >> 2) * 32;
        #pragma unroll
        for (int mt = 0; mt < 4; ++mt)
            #pragma unroll
            for (int nt = 0; nt < 2; ++nt) acc1[mt][nt] = (f32x4){0.f, 0.f, 0.f, 0.f};

        #pragma unroll
        for (int ks = 0; ks < 8; ++ks) {
            bf16x8 af[4], bf[2];
            #pragma unroll
            for (int mt = 0; mt < 4; ++mt) {
                int ar = aw + mt * 16 + lr;
                int bo = (ar * 512 + (ks * 32 + lg * 8) * 2) ^ ((ar & 7) << 4);
                af[mt] = *(const bf16x8*)(smem + bo);
            }
            #pragma unroll
            for (int nt = 0; nt < 2; ++nt)
                bf[nt] = *(const bf16x8*)(EeB + (kw + nt * 16 + lr) * H2 + ks * 32 + lg * 8);
            #pragma unroll
            for (int mt = 0; mt < 4; ++mt)
                #pragma unroll
                for (int nt = 0; nt < 2; ++nt)
                    acc1[mt][nt] = __builtin_amdgcn_mfma_f32_16x16x32_bf16(af[mt], bf[nt], acc1[mt][nt], 0, 0, 0);
        }
    }
    __syncthreads();   // slab fully consumed

    // ---- write WT[k][a] bf16 swz into smem[0:64K]
    {
        const int aw = (w & 3) * 64;
        const int kw = (w >> 2) * 32;
        #pragma unroll
        for (int mt = 0; mt < 4; ++mt)
            #pragma unroll
            for (int nt = 0; nt < 2; ++nt) {
                int k  = kw + nt * 16 + lr;
                int a0 = aw + mt * 16 + lg * 4;
                unsigned short h4[4] = { f2bf(acc1[mt][nt][0]), f2bf(acc1[mt][nt][1]),
                                         f2bf(acc1[mt][nt][2]), f2bf(acc1[mt][nt][3]) };
                int bo = (k * 512 + a0 * 2) ^ ((k & 7) << 4);
                *(uint2*)(smem + bo) = *(uint2*)h4;
            }
    }
    __syncthreads();

    // ---- P2: out[b][k][i]; 16 waves: kw2 = w>>3 (64k), iw = w&7 (16i)
    {
        const int kw2 = (w >> 3) * 64;
        const int iw  = (w & 7) * 16;
        f32x4 acc2[4];
        #pragma unroll
        for (int mt = 0; mt < 4; ++mt) acc2[mt] = (f32x4){0.f, 0.f, 0.f, 0.f};

        #pragma unroll
        for (int ks = 0; ks < 8; ++ks) {
            bf16x8 af[4], bf;
            #pragma unroll
            for (int mt = 0; mt < 4; ++mt) {
                int kr = kw2 + mt * 16 + lr;
                int bo = (kr * 512 + (ks * 32 + lg * 8) * 2) ^ ((kr & 7) << 4);
                af[mt] = *(const bf16x8*)(smem + bo);
            }
            bf = *(const bf16x8*)(Hx + (iw + lr) * H2 + ks * 32 + lg * 8);
            #pragma unroll
            for (int mt = 0; mt < 4; ++mt)
                acc2[mt] = __builtin_amdgcn_mfma_f32_16x16x32_bf16(af[mt], bf, acc2[mt], 0, 0, 0);
        }
        unsigned short* po = outp + (size_t)b * (128 * 128);
        #pragma unroll
        for (int mt = 0; mt < 4; ++mt)
            #pragma unroll
            for (int r = 0; r < 4; ++r) {
                int k = kw2 + mt * 16 + lg * 4 + r;
                int i = iw + lr;
                po[k * 128 + i] = f2bf(acc2[mt][r]);
            }
    }
}

// ---------------- trT: [b][k][i] -> [k][i][b] (both tensors), LDS tile transpose ----------
// grid 256 = t(2) x k(128); 256 thr; LDS 64KB [i][b] swizzled.
__global__ __launch_bounds__(256)
void trT(const unsigned short* __restrict__ hepN, const unsigned short* __restrict__ tepN,
         unsigned short* __restrict__ hepT, unsigned short* __restrict__ tepT)
{
    __shared__ unsigned short L[128 * 256];   // 64 KB
    const int t = blockIdx.x >> 7;
    const int k = blockIdx.x & 127;
    const unsigned short* src = t ? tepN : hepN;
    unsigned short* dst = (t ? tepT : hepT) + (size_t)k * 32768;
    const int tid = threadIdx.x;

    // in: granule g = b*16 + i8; read 8 consecutive i at (b,k)
    #pragma unroll
    for (int it = 0; it < 16; ++it) {
        int g = it * 256 + tid;
        int b = g >> 4, i8 = g & 15;
        bf16x8 v = *(const bf16x8*)(src + (size_t)b * 16384 + k * 128 + i8 * 8);
        #pragma unroll
        for (int e = 0; e < 8; ++e) {
            int i = i8 * 8 + e;
            int bo = (i * 512 + b * 2) ^ ((i8 & 7) << 4);
            *(unsigned short*)((char*)L + bo) = ((unsigned short*)&v)[e];
        }
    }
    __syncthreads();

    // out: row i, contiguous b; write coalesced
    #pragma unroll
    for (int it = 0; it < 16; ++it) {
        int h = it * 256 + tid;
        int i = h >> 5, ch = h & 31;
        int bo = (i * 512 + ch * 16) ^ (((i >> 3) & 7) << 4);
        bf16x8 v = *(const bf16x8*)((const char*)L + bo);
        *(bf16x8*)(dst + i * 256 + ch * 8) = v;
    }
}

// ---------------- step3v2: block (k, j-quarter); 32KB LDS -> high occupancy ----------
// G1: W[j][c] = sum_b tepT[k][j][b] * TclsB[m][c][b];  G2: P[i][j] = sum_c hepT[k][i][c]*W[j][c]
// grid 512 (XCD-swizzled: all 4 jq of a k on one XCD); 512 thr = 8 waves.
__global__ __launch_bounds__(512)
void step3v2(const unsigned short* __restrict__ hepT,  // [k][i][c]
             const unsigned short* __restrict__ tepT,  // [k][j][b]
             const unsigned short* __restrict__ TclsB, // [m][c][b]
             float* __restrict__ predT)                // [k*5+m][i][j]
{
    __shared__ unsigned short tepS[32 * 256];  // 16 KB swz
    __shared__ unsigned short WS[32 * 256];    // 16 KB swz
    const int lbid = ((int)blockIdx.x & 7) * 64 + ((int)blockIdx.x >> 3);
    const int k  = lbid >> 2;
    const int jq = lbid & 3;
    const int j0 = jq * 32;
    const int tid = threadIdx.x;
    const int w = tid >> 6, l = tid & 63;
    const int lr = l & 15, lg = l >> 4;

    // ---- stage tepS[j'][b] (32 rows), vector loads + swizzled vector writes
    #pragma unroll
    for (int it = 0; it < 2; ++it) {
        int g = it * 512 + tid;
        int row = g >> 5, ch = g & 31;
        bf16x8 v = *(const bf16x8*)(tepT + ((size_t)k * 128 + j0 + row) * 256 + ch * 8);
        int bo = (row * 512 + ch * 16) ^ ((row & 7) << 4);
        *(bf16x8*)((char*)tepS + bo) = v;
    }

    // ---- preload ha: wave w owns i-tile w*16 (direct vector loads from hepT)
    bf16x8 ha[8];
    #pragma unroll
    for (int ks = 0; ks < 8; ++ks)
        ha[ks] = *(const bf16x8*)(hepT + ((size_t)k * 128 + w * 16 + lr) * 256 + ks * 32 + lg * 8);
    __syncthreads();

    #pragma unroll 1
    for (int m = 0; m < NCLS; ++m) {
        // ---- G1: wave computes W[32 j][c-slice w*32..+32]
        {
            const unsigned short* tcm = TclsB + (size_t)m * (H2 * H2);
            f32x4 a1[2][2];
            #pragma unroll
            for (int jt = 0; jt < 2; ++jt)
                #pragma unroll
                for (int ct = 0; ct < 2; ++ct) a1[jt][ct] = (f32x4){0.f, 0.f, 0.f, 0.f};

            #pragma unroll
            for (int ks = 0; ks < 8; ++ks) {
                bf16x8 a[2], bb[2];
                #pragma unroll
                for (int jt = 0; jt < 2; ++jt) {
                    int bo = ((jt * 16 + lr) * 512 + (ks * 32 + lg * 8) * 2) ^ ((lr & 7) << 4);
                    a[jt] = *(const bf16x8*)((const char*)tepS + bo);
                }
                #pragma unroll
                for (int ct = 0; ct < 2; ++ct)
                    bb[ct] = *(const bf16x8*)(tcm + (size_t)(w * 32 + ct * 16 + lr) * H2 + ks * 32 + lg * 8);
                #pragma unroll
                for (int jt = 0; jt < 2; ++jt)
                    #pragma unroll
                    for (int ct = 0; ct < 2; ++ct)
                        a1[jt][ct] = __builtin_amdgcn_mfma_f32_16x16x32_bf16(a[jt], bb[ct], a1[jt][ct], 0, 0, 0);
            }
            #pragma unroll
            for (int jt = 0; jt < 2; ++jt)
                #pragma unroll
                for (int ct = 0; ct < 2; ++ct)
                    #pragma unroll
                    for (int r = 0; r < 4; ++r) {
                        int j = jt * 16 + lg * 4 + r;
                        int c = w * 32 + ct * 16 + lr;
                        int bo = (j * 512 + c * 2) ^ ((j & 7) << 4);
                        *(unsigned short*)((char*)WS + bo) = f2bf(a1[jt][ct][r]);
                    }
        }
        __syncthreads();

        // ---- G2: wave computes P[i-tile w*16][32 j]
        {
            f32x4 a2[2];
            #pragma unroll
            for (int jt = 0; jt < 2; ++jt) a2[jt] = (f32x4){0.f, 0.f, 0.f, 0.f};

            #pragma unroll
            for (int ks = 0; ks < 8; ++ks) {
                #pragma unroll
                for (int jt = 0; jt < 2; ++jt) {
                    int bo = ((jt * 16 + lr) * 512 + (ks * 32 + lg * 8) * 2) ^ ((lr & 7) << 4);
                    bf16x8 wb = *(const bf16x8*)((const char*)WS + bo);
                    a2[jt] = __builtin_amdgcn_mfma_f32_16x16x32_bf16(ha[ks], wb, a2[jt], 0, 0, 0);
                }
            }
            float* po = predT + (size_t)(k * NCLS + m) * (NENT * NENT);
            #pragma unroll
            for (int jt = 0; jt < 2; ++jt)
                #pragma unroll
                for (int r = 0; r < 4; ++r) {
                    int i = w * 16 + lg * 4 + r;
                    int j = j0 + jt * 16 + lr;
                    po[i * NENT + j] = a2[jt][r];
                }
        }
        __syncthreads();
    }
}

// ---------------- transpose: predT[km][ij] -> out[ij][km] ----------------
__global__ __launch_bounds__(256)
void transpose_out(const float* __restrict__ predT, float* __restrict__ out)
{
    __shared__ float Ls[160][33];
    const int bid = blockIdx.x;
    const int ij0 = (bid >> 2) * 32;
    const int km0 = (bid & 3) * 160;
    const int t = threadIdx.x;

    #pragma unroll
    for (int q = 0; q < 20; ++q) {
        int r = (t >> 5) + q * 8;
        int c = t & 31;
        Ls[r][c] = predT[(size_t)(km0 + r) * 16384 + ij0 + c];
    }
    __syncthreads();
    for (int idx = t; idx < 32 * 160; idx += 256) {
        int r = idx / 160, c = idx % 160;
        out[(size_t)(ij0 + r) * 640 + km0 + c] = Ls[c][r];
    }
}

extern "C" void kernel_launch(void* const* d_in, const int* in_sizes, int n_in,
                              void* d_out, int out_size, void* d_ws, size_t ws_size,
                              hipStream_t stream)
{
    (void)in_sizes; (void)n_in; (void)out_size; (void)ws_size;
    const float* enc  = (const float*)d_in[0];
    const int*   hidx = (const int*)d_in[1];
    const int*   tidx = (const int*)d_in[2];
    const int*   eidx = (const int*)d_in[3];
    const float* Whf = (const float*)d_in[4];
    const float* bhf = (const float*)d_in[5];
    const float* Whb = (const float*)d_in[6];
    const float* bhb = (const float*)d_in[7];
    const float* Wtf = (const float*)d_in[8];
    const float* btf = (const float*)d_in[9];
    const float* Wtb = (const float*)d_in[10];
    const float* btb = (const float*)d_in[11];
    const float* Wef = (const float*)d_in[12];
    const float* bef = (const float*)d_in[13];
    const float* Web = (const float*)d_in[14];
    const float* beb = (const float*)d_in[15];
    const float* T_he  = (const float*)d_in[16];
    const float* T_te  = (const float*)d_in[17];
    const float* T_cls = (const float*)d_in[18];

    float* out = (float*)d_out;
    char*  ws  = (char*)d_ws;
    unsigned short* poolB  = (unsigned short*)(ws + POOLB_OFF);
    unsigned short* TclsB  = (unsigned short*)(ws + TCLSB_OFF);
    unsigned short* hepT   = (unsigned short*)(ws + HEPT_OFF);
    unsigned short* tepT   = (unsigned short*)(ws + TEPT_OFF);
    unsigned short* hepN   = (unsigned short*)(ws + HEPN_OFF);
    unsigned short* tepN   = (unsigned short*)(ws + TEPN_OFF);
    unsigned short* gatesB = (unsigned short*)(ws + GATESB_OFF);
    float*          predT  = (float*)(ws + PREDT_OFF);
    unsigned short* WB     = (unsigned short*)(ws + WB_OFF);
    unsigned short* tokB   = (unsigned short*)(ws + TOKB_OFF);

    unsigned short* HeB = poolB;
    unsigned short* TeB = poolB + 1 * NENT * H2;
    unsigned short* EeB = poolB + 2 * NENT * H2;

    prep_kernel<<<7616, 256, 0, stream>>>(Whf, Whb, Wtf, Wtb, Wef, Web,
                                          T_cls, enc, hidx, tidx, eidx,
                                          WB, TclsB, tokB);

    gates_mfma<<<288, 256, 0, stream>>>(tokB, WB, gatesB);

    pool_epilogue<<<384, 256, 0, stream>>>(gatesB, bhf, bhb, btf, btb, bef, beb, poolB);

    pair_mfma<<<512, 1024, 0, stream>>>(EeB, HeB, TeB, T_he, T_te, hepN, tepN);

    trT<<<256, 256, 0, stream>>>(hepN, tepN, hepT, tepT);

    step3v2<<<512, 512, 0, stream>>>(hepT, tepT, TclsB, predT);

    transpose_out<<<2048, 256, 0, stream>>>(predT, out);
}

// Round 19
// 147.693 us; speedup vs baseline: 1.1877x; 1.0330x over previous
//
#include <hip/hip_runtime.h>
#include <hip/hip_bf16.h>
#include <math.h>

#define DIM   768
#define HID   128
#define H2    256
#define NENT  128
#define SPAN  16
#define NCLS  5

// ---- ws layout (bytes); peak 72,548,352 <= 73,596,928 proven ----
// poolB  @0          (196,608)
// TclsB  @196,608    (655,360)
// hepN   @851,968    (8,388,608)  [b][k][i]   pair->step3
// tepN   @9,240,576  (8,388,608)  [b][k][j]   pair->step3
// gatesB @17,629,184 (9,437,184)  gates->pool (dead before predT)
// predT  @17,629,184 (41,943,040) step3->transpose (ends 59,572,224)
// WB     @59,572,224 (3,538,944)  prep->gates
// tokB   @63,111,168 (9,437,184)  prep->gates (ends 72,548,352)
#define POOLB_OFF  0
#define TCLSB_OFF  196608
#define HEPN_OFF   851968
#define TEPN_OFF   9240576
#define GATESB_OFF 17629184
#define PREDT_OFF  17629184
#define WB_OFF     59572224
#define TOKB_OFF   63111168

typedef __attribute__((ext_vector_type(8))) short bf16x8;
typedef __attribute__((ext_vector_type(4))) float f32x4;

__device__ __forceinline__ float sigmoidf_(float x) { return 1.0f / (1.0f + __expf(-x)); }

__device__ __forceinline__ unsigned short f2bf(float x) {
    __hip_bfloat16 h = __float2bfloat16(x);
    return *reinterpret_cast<unsigned short*>(&h);
}
__device__ __forceinline__ float bf2f(unsigned short u) {
    unsigned int v = ((unsigned int)u) << 16;
    float f; __builtin_memcpy(&f, &v, 4); return f;
}

// ---------------- prep: wconv + conv_tcls + gather_toks fused ----------------
__global__ __launch_bounds__(256)
void prep_kernel(const float* __restrict__ Whf, const float* __restrict__ Whb,
                 const float* __restrict__ Wtf, const float* __restrict__ Wtb,
                 const float* __restrict__ Wef, const float* __restrict__ Web,
                 const float* __restrict__ Tcls, const float* __restrict__ enc,
                 const int* __restrict__ idx_h, const int* __restrict__ idx_t,
                 const int* __restrict__ idx_e,
                 unsigned short* __restrict__ WB, unsigned short* __restrict__ TB,
                 unsigned short* __restrict__ tokB)
{
    const int bb = blockIdx.x;
    const int tid = threadIdx.x;
    if (bb < 1728) {
        int gid = bb * 256 + tid;                        // < 442368
        int t2  = gid / 73728;
        int rem = gid % 73728;
        int n   = rem / 192;
        int c4  = rem % 192;
        int gate = n >> 7, j = n & 127;
        int srow = (gate == 0) ? j : (gate == 1) ? 256 + j : 384 + j;
        const float* W = (t2 == 0) ? Whf : (t2 == 1) ? Whb : (t2 == 2) ? Wtf :
                         (t2 == 3) ? Wtb : (t2 == 4) ? Wef : Web;
        float4 v = ((const float4*)(W + srow * DIM))[c4];
        unsigned short* d = WB + ((size_t)(t2 * 384 + n)) * DIM + c4 * 4;
        d[0] = f2bf(v.x); d[1] = f2bf(v.y); d[2] = f2bf(v.z); d[3] = f2bf(v.w);
    } else if (bb < 3008) {
        int idx = (bb - 1728) * 256 + tid;               // < 327680
        int b = idx / (NCLS * H2);
        int r = idx % (NCLS * H2);
        int m = r >> 8, c = r & 255;
        TB[((m << 8) + c) * H2 + b] = f2bf(Tcls[idx]);
    } else {
        int gid = (bb - 3008) * 256 + tid;               // < 6144*192
        int r  = gid / 192, c4 = gid % 192;
        int type = r >> 11;
        int rem  = r & 2047;
        const int* idx = (type == 0) ? idx_h : (type == 1) ? idx_t : idx_e;
        int row = idx[rem];
        float4 v = ((const float4*)(enc + (size_t)row * DIM))[c4];
        unsigned short h4[4] = { f2bf(v.x), f2bf(v.y), f2bf(v.z), f2bf(v.w) };
        *(uint2*)(tokB + (size_t)r * DIM + c4 * 4) = *(uint2*)h4;
    }
}

// ---------------- gates GEMM (NT), LDS-staged 2-phase double-buffer; bf16 out ----------------
__global__ __launch_bounds__(256)
void gates_mfma(const unsigned short* __restrict__ tokB,
                const unsigned short* __restrict__ WB,
                unsigned short* __restrict__ gatesB)
{
    __shared__ unsigned short As[2][128 * 64];
    __shared__ unsigned short Bs[2][128 * 64];
    const int lbid = ((int)blockIdx.x & 7) * 36 + ((int)blockIdx.x >> 3);  // bijective
    const int type = lbid / 96;
    const int rem  = lbid % 96;
    const int mb0  = (rem / 6) * 128;
    const int nb0  = (rem % 6) * 128;
    const int tid = threadIdx.x;
    const int w = tid >> 6, l = tid & 63;
    const int lr = l & 15, lg = l >> 4;
    const unsigned short* A = tokB + (size_t)type * 2048 * DIM + (size_t)mb0 * DIM;
    const unsigned short* B = WB   + (size_t)type * 768  * DIM + (size_t)nb0 * DIM;

    const int sr0 = tid >> 3;
    const int sc  = tid & 7;

    bf16x8 ra[4], rb[4];
    #define LOADT(kt)                                                        \
        {                                                                    \
            const int koff = (kt) * 64 + sc * 8;                             \
            _Pragma("unroll")                                                \
            for (int p = 0; p < 4; ++p) {                                    \
                int rr = sr0 + p * 32;                                       \
                ra[p] = *(const bf16x8*)(A + (size_t)rr * DIM + koff);       \
                rb[p] = *(const bf16x8*)(B + (size_t)rr * DIM + koff);       \
            }                                                                \
        }
    #define WRITET(buf)                                                      \
        {                                                                    \
            _Pragma("unroll")                                                \
            for (int p = 0; p < 4; ++p) {                                    \
                int rr = sr0 + p * 32;                                       \
                int bo = (rr * 128 + sc * 16) ^ ((rr & 7) << 4);             \
                *(bf16x8*)((char*)As[buf] + bo) = ra[p];                     \
                *(bf16x8*)((char*)Bs[buf] + bo) = rb[p];                     \
            }                                                                \
        }

    f32x4 acc[4][4];
    #pragma unroll
    for (int mt = 0; mt < 4; ++mt)
        #pragma unroll
        for (int nt = 0; nt < 4; ++nt) acc[mt][nt] = (f32x4){0.f, 0.f, 0.f, 0.f};

    const int am0 = (w & 1) * 64;
    const int bn0 = (w >> 1) * 64;

    LOADT(0);
    WRITET(0);
    __syncthreads();

    int cur = 0;
    #pragma unroll 1
    for (int kt = 0; kt < 12; ++kt) {
        if (kt + 1 < 12) LOADT(kt + 1);

        #pragma unroll
        for (int ks = 0; ks < 2; ++ks) {
            bf16x8 af[4], bf[4];
            #pragma unroll
            for (int mt = 0; mt < 4; ++mt) {
                int rr = am0 + mt * 16 + lr;
                int bo = (rr * 128 + ks * 64 + lg * 16) ^ ((rr & 7) << 4);
                af[mt] = *(const bf16x8*)((const char*)As[cur] + bo);
            }
            #pragma unroll
            for (int nt = 0; nt < 4; ++nt) {
                int rr = bn0 + nt * 16 + lr;
                int bo = (rr * 128 + ks * 64 + lg * 16) ^ ((rr & 7) << 4);
                bf[nt] = *(const bf16x8*)((const char*)Bs[cur] + bo);
            }
            #pragma unroll
            for (int mt = 0; mt < 4; ++mt)
                #pragma unroll
                for (int nt = 0; nt < 4; ++nt)
                    acc[mt][nt] = __builtin_amdgcn_mfma_f32_16x16x32_bf16(af[mt], bf[nt], acc[mt][nt], 0, 0, 0);
        }

        if (kt + 1 < 12) {
            WRITET(cur ^ 1);
        }
        __syncthreads();
        cur ^= 1;
    }
    #undef LOADT
    #undef WRITET

    unsigned short* C = gatesB + (size_t)type * 2048 * 768 + (size_t)mb0 * 768 + nb0;
    #pragma unroll
    for (int mt = 0; mt < 4; ++mt)
        #pragma unroll
        for (int nt = 0; nt < 4; ++nt)
            #pragma unroll
            for (int r = 0; r < 4; ++r)
                C[(size_t)(am0 + mt * 16 + lg * 4 + r) * 768 + bn0 + nt * 16 + lr] = f2bf(acc[mt][nt][r]);
}

// ---------------- pool epilogue (bf16 gates) ----------------
__global__ __launch_bounds__(256)
void pool_epilogue(const unsigned short* __restrict__ gatesB,
                   const float* __restrict__ bhf, const float* __restrict__ bhb,
                   const float* __restrict__ btf, const float* __restrict__ btb,
                   const float* __restrict__ bef, const float* __restrict__ beb,
                   unsigned short* __restrict__ poolB)
{
    const int type = blockIdx.x >> 7;
    const int ent  = blockIdx.x & 127;
    const int tid  = threadIdx.x;
    const int dir  = tid >> 7;
    const int j    = tid & 127;
    const float* Bv = (type == 0) ? (dir ? bhb : bhf)
                    : (type == 1) ? (dir ? btb : btf)
                                  : (dir ? beb : bef);
    const float bi = Bv[j], bg = Bv[2 * HID + j], bo = Bv[3 * HID + j];
    const unsigned short* g0 = gatesB + ((size_t)type * 2048 + ent * 16) * 768 + dir * 384 + j;
    float hmax = -1e30f;
    #pragma unroll
    for (int ll = 0; ll < SPAN; ++ll) {
        const unsigned short* gr = g0 + ll * 768;
        float iv = sigmoidf_(bf2f(gr[0])   + bi);
        float gv = tanhf(   bf2f(gr[128]) + bg);
        float ov = sigmoidf_(bf2f(gr[256]) + bo);
        hmax = fmaxf(hmax, ov * tanhf(iv * gv));
    }
    poolB[(size_t)(type * NENT + ent) * H2 + dir * HID + j] = f2bf(hmax);
}

// ---------------- pair: fused gemm1+gemm2 (r11 best-measured T-path) ----------------
__global__ __launch_bounds__(1024)
void pair_mfma(const unsigned short* __restrict__ EeB,
               const unsigned short* __restrict__ HeB,
               const unsigned short* __restrict__ TeB,
               const float* __restrict__ T0, const float* __restrict__ T1,
               unsigned short* __restrict__ hepN,   // [256 b][128 k][128 i]
               unsigned short* __restrict__ tepN)
{
    __shared__ __align__(16) char smem[131072];
    const int bid = blockIdx.x;
    const int t = bid >> 8;
    const int b = bid & 255;
    const float* T = t ? T1 : T0;
    const unsigned short* Hx = t ? TeB : HeB;
    unsigned short* outp = t ? tepN : hepN;
    const int tid = threadIdx.x;
    const int w = tid >> 6, l = tid & 63;
    const int lr = l & 15, lg = l >> 4;

    // ---- stage T[:,b,:] fp32 -> slab bf16 swz (conflict-free mapping)
    {
        const int r0 = tid >> 5;
        const int ch = tid & 31;
        #pragma unroll
        for (int p = 0; p < 8; ++p) {
            int row = p * 32 + r0;
            const float* src = T + ((size_t)row * 256 + b) * 256 + ch * 8;
            float4 v0 = ((const float4*)src)[0];
            float4 v1 = ((const float4*)src)[1];
            bf16x8 hv; unsigned short* hp = (unsigned short*)&hv;
            hp[0]=f2bf(v0.x); hp[1]=f2bf(v0.y); hp[2]=f2bf(v0.z); hp[3]=f2bf(v0.w);
            hp[4]=f2bf(v1.x); hp[5]=f2bf(v1.y); hp[6]=f2bf(v1.z); hp[7]=f2bf(v1.w);
            int bo = (row * 512 + ch * 16) ^ ((row & 7) << 4);
            *(bf16x8*)(smem + bo) = hv;
        }
    }
    __syncthreads();

    // ---- P1: W[a][k]; 16 waves: aw = w&3 (64a), kw = w>>2 (32k)
    f32x4 acc1[4][2];
    {
        const int aw = (w & 3) * 64;
        const int kw = (w >> 2) * 32;
        #pragma unroll
        for (int mt = 0; mt < 4; ++mt)
            #pragma unroll
            for (int nt = 0; nt < 2; ++nt) acc1[mt][nt] = (f32x4){0.f, 0.f, 0.f, 0.f};

        #pragma unroll
        for (int ks = 0; ks < 8; ++ks) {
            bf16x8 af[4], bf[2];
            #pragma unroll
            for (int mt = 0; mt < 4; ++mt) {
                int ar = aw + mt * 16 + lr;
                int bo = (ar * 512 + (ks * 32 + lg * 8) * 2) ^ ((ar & 7) << 4);
                af[mt] = *(const bf16x8*)(smem + bo);
            }
            #pragma unroll
            for (int nt = 0; nt < 2; ++nt)
                bf[nt] = *(const bf16x8*)(EeB + (kw + nt * 16 + lr) * H2 + ks * 32 + lg * 8);
            #pragma unroll
            for (int mt = 0; mt < 4; ++mt)
                #pragma unroll
                for (int nt = 0; nt < 2; ++nt)
                    acc1[mt][nt] = __builtin_amdgcn_mfma_f32_16x16x32_bf16(af[mt], bf[nt], acc1[mt][nt], 0, 0, 0);
        }
    }
    __syncthreads();   // slab fully consumed

    // ---- write WT[k][a] bf16 swz into smem[0:64K]
    {
        const int aw = (w & 3) * 64;
        const int kw = (w >> 2) * 32;
        #pragma unroll
        for (int mt = 0; mt < 4; ++mt)
            #pragma unroll
            for (int nt = 0; nt < 2; ++nt) {
                int k  = kw + nt * 16 + lr;
                int a0 = aw + mt * 16 + lg * 4;
                unsigned short h4[4] = { f2bf(acc1[mt][nt][0]), f2bf(acc1[mt][nt][1]),
                                         f2bf(acc1[mt][nt][2]), f2bf(acc1[mt][nt][3]) };
                int bo = (k * 512 + a0 * 2) ^ ((k & 7) << 4);
                *(uint2*)(smem + bo) = *(uint2*)h4;
            }
    }
    __syncthreads();

    // ---- P2: out[b][k][i]; 16 waves: kw2 = w>>3 (64k), iw = w&7 (16i)
    {
        const int kw2 = (w >> 3) * 64;
        const int iw  = (w & 7) * 16;
        f32x4 acc2[4];
        #pragma unroll
        for (int mt = 0; mt < 4; ++mt) acc2[mt] = (f32x4){0.f, 0.f, 0.f, 0.f};

        #pragma unroll
        for (int ks = 0; ks < 8; ++ks) {
            bf16x8 af[4], bf;
            #pragma unroll
            for (int mt = 0; mt < 4; ++mt) {
                int kr = kw2 + mt * 16 + lr;
                int bo = (kr * 512 + (ks * 32 + lg * 8) * 2) ^ ((kr & 7) << 4);
                af[mt] = *(const bf16x8*)(smem + bo);
            }
            bf = *(const bf16x8*)(Hx + (iw + lr) * H2 + ks * 32 + lg * 8);
            #pragma unroll
            for (int mt = 0; mt < 4; ++mt)
                acc2[mt] = __builtin_amdgcn_mfma_f32_16x16x32_bf16(af[mt], bf, acc2[mt], 0, 0, 0);
        }
        unsigned short* po = outp + (size_t)b * (128 * 128);
        #pragma unroll
        for (int mt = 0; mt < 4; ++mt)
            #pragma unroll
            for (int r = 0; r < 4; ++r) {
                int k = kw2 + mt * 16 + lg * 4 + r;
                int i = iw + lr;
                po[k * 128 + i] = f2bf(acc2[mt][r]);
            }
    }
}

// ---------------- step3v3: block (k, j-quarter); in-kernel transposes; 48KB LDS ----------
// G1: W[j][c] = sum_b tep[k][j][b]*TclsB[m][c][b];  G2: P[i][j] = sum_c hep[k][i][c]*W[j][c]
// tepS [32j][256b] swz (16K); bufA [64i][256c] swz (32K, hep staged in 2 halves);
// WS [32j][256c] (16K) aliases bufA after ha extraction. grid 512 XCD-swizzled; 512 thr.
__global__ __launch_bounds__(512)
void step3v3(const unsigned short* __restrict__ hepN,  // [b][k][i]  (b == c of hep)
             const unsigned short* __restrict__ tepN,  // [b][k][j]
             const unsigned short* __restrict__ TclsB, // [m][c][b]
             float* __restrict__ predT)                // [k*5+m][i][j]
{
    __shared__ __align__(16) char smem[49152];
    char* tepS = smem;           // 16 KB
    char* bufA = smem + 16384;   // 32 KB (dead after ha extraction)
    char* WS   = smem + 16384;   // 16 KB alias
    const int lbid = ((int)blockIdx.x & 7) * 64 + ((int)blockIdx.x >> 3);
    const int k  = lbid >> 2;
    const int jq = lbid & 3;
    const int j0 = jq * 32;
    const int tid = threadIdx.x;
    const int w = tid >> 6, l = tid & 63;
    const int lr = l & 15, lg = l >> 4;

    // ---- stage tepS[j][b] from tepN (lanes b-major: ~2-way conflicts)
    #pragma unroll
    for (int it = 0; it < 2; ++it) {
        int g = it * 512 + tid;
        int b = g & 255, j8 = g >> 8;
        bf16x8 v = *(const bf16x8*)(tepN + (size_t)b * 16384 + k * 128 + j0 + j8 * 8);
        #pragma unroll
        for (int e = 0; e < 8; ++e) {
            int j = j8 * 8 + e;
            int bo = (j * 512 + b * 2) ^ (e << 4);
            *(unsigned short*)(tepS + bo) = ((unsigned short*)&v)[e];
        }
    }

    bf16x8 ha[8];
    // ---- hep half 0 (rows i 0..63) into bufA
    #pragma unroll
    for (int it = 0; it < 4; ++it) {
        int g = it * 512 + tid;
        int b = g & 255, i8 = g >> 8;
        bf16x8 v = *(const bf16x8*)(hepN + (size_t)b * 16384 + k * 128 + i8 * 8);
        #pragma unroll
        for (int e = 0; e < 8; ++e) {
            int il = i8 * 8 + e;
            int bo = (il * 512 + b * 2) ^ (e << 4);
            *(unsigned short*)(bufA + bo) = ((unsigned short*)&v)[e];
        }
    }
    __syncthreads();
    if (w < 4) {
        int il = (w & 3) * 16 + lr;
        #pragma unroll
        for (int ks = 0; ks < 8; ++ks) {
            int bo = (il * 512 + (ks * 32 + lg * 8) * 2) ^ ((il & 7) << 4);
            ha[ks] = *(const bf16x8*)(bufA + bo);
        }
    }
    __syncthreads();
    // ---- hep half 1 (rows i 64..127)
    #pragma unroll
    for (int it = 0; it < 4; ++it) {
        int g = it * 512 + tid;
        int b = g & 255, i8 = g >> 8;
        bf16x8 v = *(const bf16x8*)(hepN + (size_t)b * 16384 + k * 128 + 64 + i8 * 8);
        #pragma unroll
        for (int e = 0; e < 8; ++e) {
            int il = i8 * 8 + e;
            int bo = (il * 512 + b * 2) ^ (e << 4);
            *(unsigned short*)(bufA + bo) = ((unsigned short*)&v)[e];
        }
    }
    __syncthreads();
    if (w >= 4) {
        int il = (w & 3) * 16 + lr;
        #pragma unroll
        for (int ks = 0; ks < 8; ++ks) {
            int bo = (il * 512 + (ks * 32 + lg * 8) * 2) ^ ((il & 7) << 4);
            ha[ks] = *(const bf16x8*)(bufA + bo);
        }
    }
    __syncthreads();   // bufA dead -> WS may alias

    #pragma unroll 1
    for (int m = 0; m < NCLS; ++m) {
        // ---- G1: wave computes W[32 j][c-slice w*32..+32]
        {
            const unsigned short* tcm = TclsB + (size_t)m * (H2 * H2);
            f32x4 a1[2][2];
            #pragma unroll
            for (int jt = 0; jt < 2; ++jt)
                #pragma unroll
                for (int ct = 0; ct < 2; ++ct) a1[jt][ct] = (f32x4){0.f, 0.f, 0.f, 0.f};

            #pragma unroll
            for (int ks = 0; ks < 8; ++ks) {
                bf16x8 a[2], bb[2];
                #pragma unroll
                for (int jt = 0; jt < 2; ++jt) {
                    int bo = ((jt * 16 + lr) * 512 + (ks * 32 + lg * 8) * 2) ^ ((lr & 7) << 4);
                    a[jt] = *(const bf16x8*)(tepS + bo);
                }
                #pragma unroll
                for (int ct = 0; ct < 2; ++ct)
                    bb[ct] = *(const bf16x8*)(tcm + (size_t)(w * 32 + ct * 16 + lr) * H2 + ks * 32 + lg * 8);
                #pragma unroll
                for (int jt = 0; jt < 2; ++jt)
                    #pragma unroll
                    for (int ct = 0; ct < 2; ++ct)
                        a1[jt][ct] = __builtin_amdgcn_mfma_f32_16x16x32_bf16(a[jt], bb[ct], a1[jt][ct], 0, 0, 0);
            }
            #pragma unroll
            for (int jt = 0; jt < 2; ++jt)
                #pragma unroll
                for (int ct = 0; ct < 2; ++ct)
                    #pragma unroll
                    for (int r = 0; r < 4; ++r) {
                        int j = jt * 16 + lg * 4 + r;
                        int c = w * 32 + ct * 16 + lr;
                        int bo = (j * 512 + c * 2) ^ ((j & 7) << 4);
                        *(unsigned short*)(WS + bo) = f2bf(a1[jt][ct][r]);
                    }
        }
        __syncthreads();

        // ---- G2: wave computes P[i-tile w*16][32 j]
        {
            f32x4 a2[2];
            #pragma unroll
            for (int jt = 0; jt < 2; ++jt) a2[jt] = (f32x4){0.f, 0.f, 0.f, 0.f};

            #pragma unroll
            for (int ks = 0; ks < 8; ++ks) {
                #pragma unroll
                for (int jt = 0; jt < 2; ++jt) {
                    int bo = ((jt * 16 + lr) * 512 + (ks * 32 + lg * 8) * 2) ^ ((lr & 7) << 4);
                    bf16x8 wb = *(const bf16x8*)(WS + bo);
                    a2[jt] = __builtin_amdgcn_mfma_f32_16x16x32_bf16(ha[ks], wb, a2[jt], 0, 0, 0);
                }
            }
            float* po = predT + (size_t)(k * NCLS + m) * (NENT * NENT);
            #pragma unroll
            for (int jt = 0; jt < 2; ++jt)
                #pragma unroll
                for (int r = 0; r < 4; ++r) {
                    int i = w * 16 + lg * 4 + r;
                    int j = j0 + jt * 16 + lr;
                    po[i * NENT + j] = a2[jt][r];
                }
        }
        __syncthreads();
    }
}

// ---------------- transpose: predT[km][ij] -> out[ij][km] ----------------
__global__ __launch_bounds__(256)
void transpose_out(const float* __restrict__ predT, float* __restrict__ out)
{
    __shared__ float Ls[160][33];
    const int bid = blockIdx.x;
    const int ij0 = (bid >> 2) * 32;
    const int km0 = (bid & 3) * 160;
    const int t = threadIdx.x;

    #pragma unroll
    for (int q = 0; q < 20; ++q) {
        int r = (t >> 5) + q * 8;
        int c = t & 31;
        Ls[r][c] = predT[(size_t)(km0 + r) * 16384 + ij0 + c];
    }
    __syncthreads();
    for (int idx = t; idx < 32 * 160; idx += 256) {
        int r = idx / 160, c = idx % 160;
        out[(size_t)(ij0 + r) * 640 + km0 + c] = Ls[c][r];
    }
}

extern "C" void kernel_launch(void* const* d_in, const int* in_sizes, int n_in,
                              void* d_out, int out_size, void* d_ws, size_t ws_size,
                              hipStream_t stream)
{
    (void)in_sizes; (void)n_in; (void)out_size; (void)ws_size;
    const float* enc  = (const float*)d_in[0];
    const int*   hidx = (const int*)d_in[1];
    const int*   tidx = (const int*)d_in[2];
    const int*   eidx = (const int*)d_in[3];
    const float* Whf = (const float*)d_in[4];
    const float* bhf = (const float*)d_in[5];
    const float* Whb = (const float*)d_in[6];
    const float* bhb = (const float*)d_in[7];
    const float* Wtf = (const float*)d_in[8];
    const float* btf = (const float*)d_in[9];
    const float* Wtb = (const float*)d_in[10];
    const float* btb = (const float*)d_in[11];
    const float* Wef = (const float*)d_in[12];
    const float* bef = (const float*)d_in[13];
    const float* Web = (const float*)d_in[14];
    const float* beb = (const float*)d_in[15];
    const float* T_he  = (const float*)d_in[16];
    const float* T_te  = (const float*)d_in[17];
    const float* T_cls = (const float*)d_in[18];

    float* out = (float*)d_out;
    char*  ws  = (char*)d_ws;
    unsigned short* poolB  = (unsigned short*)(ws + POOLB_OFF);
    unsigned short* TclsB  = (unsigned short*)(ws + TCLSB_OFF);
    unsigned short* hepN   = (unsigned short*)(ws + HEPN_OFF);
    unsigned short* tepN   = (unsigned short*)(ws + TEPN_OFF);
    unsigned short* gatesB = (unsigned short*)(ws + GATESB_OFF);
    float*          predT  = (float*)(ws + PREDT_OFF);
    unsigned short* WB     = (unsigned short*)(ws + WB_OFF);
    unsigned short* tokB   = (unsigned short*)(ws + TOKB_OFF);

    unsigned short* HeB = poolB;
    unsigned short* TeB = poolB + 1 * NENT * H2;
    unsigned short* EeB = poolB + 2 * NENT * H2;

    prep_kernel<<<7616, 256, 0, stream>>>(Whf, Whb, Wtf, Wtb, Wef, Web,
                                          T_cls, enc, hidx, tidx, eidx,
                                          WB, TclsB, tokB);

    gates_mfma<<<288, 256, 0, stream>>>(tokB, WB, gatesB);

    pool_epilogue<<<384, 256, 0, stream>>>(gatesB, bhf, bhb, btf, btb, bef, beb, poolB);

    pair_mfma<<<512, 1024, 0, stream>>>(EeB, HeB, TeB, T_he, T_te, hepN, tepN);

    step3v3<<<512, 512, 0, stream>>>(hepN, tepN, TclsB, predT);

    transpose_out<<<2048, 256, 0, stream>>>(predT, out);
}